// Round 3
// baseline (3961.159 us; speedup 1.0000x reference)
//
#include <hip/hip_runtime.h>
#include <math.h>

#define NEG_SLOPE 0.2f

__device__ __forceinline__ void atomAddF(float* p, float v) {
    unsafeAtomicAdd(p, v);  // HW global_atomic_add_f32
}
__device__ __forceinline__ float lrelu(float x) { return x > 0.f ? x : NEG_SLOPE * x; }
__device__ __forceinline__ float elu1(float x) { return x > 0.f ? x : expf(x) - 1.f; }

__device__ __forceinline__ float wredmax(float v) {
    #pragma unroll
    for (int m = 32; m; m >>= 1) v = fmaxf(v, __shfl_xor(v, m));
    return v;
}
__device__ __forceinline__ float wredsum(float v) {
    #pragma unroll
    for (int m = 32; m; m >>= 1) v += __shfl_xor(v, m);
    return v;
}
__device__ __forceinline__ float hredsum(float v) {  // within 32-lane half
    #pragma unroll
    for (int m = 16; m; m >>= 1) v += __shfl_xor(v, m);
    return v;
}

// ---- K0: in-degree (int) + edge_attr sum per dst ----
__global__ void k0_deg(const int* __restrict__ dst, const float* __restrict__ ea,
                       int* __restrict__ cnt, float* __restrict__ asum, int E) {
    int t = blockIdx.x * blockDim.x + threadIdx.x;
    if (t >= E) return;
    int d = dst[t];
    atomicAdd(&cnt[d], 1);
    atomAddF(&asum[d], ea[t]);
}

// ---- scan: rowstart = exclusive_scan(cnt[i]+1) ----
__global__ void kscanA(const int* __restrict__ cnt, int* __restrict__ rowstart,
                       int* __restrict__ bsum, int N) {
    __shared__ int sm[256];
    int t = threadIdx.x;
    int i = blockIdx.x * 256 + t;
    int v = (i < N) ? (cnt[i] + 1) : 0;
    sm[t] = v;
    __syncthreads();
    for (int off = 1; off < 256; off <<= 1) {
        int u = (t >= off) ? sm[t - off] : 0;
        __syncthreads();
        sm[t] += u;
        __syncthreads();
    }
    if (i < N) rowstart[i] = sm[t] - v;
    if (t == 255) bsum[blockIdx.x] = sm[255];
}

__global__ void kscanB(int* __restrict__ bsum, int B) {
    __shared__ int sm[512];
    int t = threadIdx.x;
    int v = (t < B) ? bsum[t] : 0;
    sm[t] = v;
    __syncthreads();
    for (int off = 1; off < 512; off <<= 1) {
        int u = (t >= off) ? sm[t - off] : 0;
        __syncthreads();
        sm[t] += u;
        __syncthreads();
    }
    if (t < B) bsum[t] = sm[t] - v;  // exclusive block offsets
}

__global__ void kscanC(int* __restrict__ rowstart, const int* __restrict__ bsum, int N) {
    int i = blockIdx.x * blockDim.x + threadIdx.x;
    if (i < N) rowstart[i] += bsum[i >> 8];
}

// ---- scatter edges into CSR (payload: src, ea, orig index) ----
__global__ void kscatter(const int* __restrict__ srcA, const int* __restrict__ dstA,
                         const float* __restrict__ ea, const float* __restrict__ asum,
                         const int* __restrict__ cnt, const int* __restrict__ rowstart,
                         int* __restrict__ cursor, int* __restrict__ srcS,
                         float* __restrict__ eaS, int* __restrict__ origS, int E, int Et) {
    int t = blockIdx.x * blockDim.x + threadIdx.x;
    if (t >= Et) return;
    int s, d; float v;
    if (t < E) { s = srcA[t]; d = dstA[t]; v = ea[t]; }
    else       { s = d = t - E; v = asum[d] / fmaxf((float)cnt[d], 1.0f); }
    int pos = rowstart[d] + atomicAdd(&cursor[d], 1);
    srcS[pos] = s; eaS[pos] = v; origS[pos] = t;
}

// ---- kL1: layer-1 per-node (wave/node): rank-2 logits, online softmax moments,
//      h = agg/den + bias1 + skip; BN partials. No atomics. ----
__global__ void kL1(const float* __restrict__ x,
                    const int* __restrict__ srcS, const float* __restrict__ eaS,
                    const int* __restrict__ rowstart, const int* __restrict__ cnt,
                    const float* __restrict__ Wl, const float* __restrict__ bl,
                    const float* __restrict__ Wr, const float* __restrict__ br,
                    const float* __restrict__ We, const float* __restrict__ att,
                    const float* __restrict__ skW, const float* __restrict__ skb,
                    const float* __restrict__ bias1,
                    float* __restrict__ hout, float* __restrict__ partial, int N) {
    __shared__ float sW[12][64];
    __shared__ float sv[256], sq[256];
    if (threadIdx.x < 64) {
        int d = threadIdx.x;
        sW[0][d] = Wl[d];   sW[1][d] = Wl[64 + d];  sW[2][d] = bl[d];
        sW[3][d] = Wr[d];   sW[4][d] = Wr[64 + d];  sW[5][d] = br[d];
        sW[6][d] = We[d];   sW[7][d] = att[d];
        sW[8][d] = skW[d];  sW[9][d] = skW[64 + d]; sW[10][d] = skb[d];
        sW[11][d] = bias1[d];
    }
    __syncthreads();
    int w = threadIdx.x >> 6, lane = threadIdx.x & 63;
    float bs = 0.f, bq = 0.f;
    for (int n = blockIdx.x * 4 + w; n < N; n += gridDim.x * 4) {
        int start = rowstart[n], len = cnt[n] + 1;
        float x0d = x[2 * n], x1d = x[2 * n + 1];
        float m0 = -1e30f, m1 = -1e30f;
        float pd0 = 0.f, pa0 = 0.f, pb0 = 0.f, pd1 = 0.f, pa1 = 0.f, pb1 = 0.f;
        for (int base = 0; base < len; base += 64) {
            int idx = base + lane;
            bool act = idx < len;
            float eav = 0.f, x0s = 0.f, x1s = 0.f;
            if (act) {
                int e = start + idx;
                int s = srcS[e]; eav = eaS[e];
                x0s = x[2 * s]; x1s = x[2 * s + 1];
            }
            float l0 = -1e30f, l1 = -1e30f;
            if (act) {
                l0 = 0.f; l1 = 0.f;
                #pragma unroll
                for (int c = 0; c < 32; ++c) {
                    float mm0 = x0s * sW[0][c] + x1s * sW[1][c] + sW[2][c]
                              + x0d * sW[3][c] + x1d * sW[4][c] + sW[5][c] + eav * sW[6][c];
                    l0 += lrelu(mm0) * sW[7][c];
                    int c2 = c + 32;
                    float mm1 = x0s * sW[0][c2] + x1s * sW[1][c2] + sW[2][c2]
                              + x0d * sW[3][c2] + x1d * sW[4][c2] + sW[5][c2] + eav * sW[6][c2];
                    l1 += lrelu(mm1) * sW[7][c2];
                }
            }
            float wm0 = wredmax(l0), wm1 = wredmax(l1);
            if (wm0 > m0) { float r = expf(m0 - wm0); pd0 *= r; pa0 *= r; pb0 *= r; m0 = wm0; }
            if (wm1 > m1) { float r = expf(m1 - wm1); pd1 *= r; pa1 *= r; pb1 *= r; m1 = wm1; }
            float ev0 = act ? expf(l0 - m0) : 0.f;
            float ev1 = act ? expf(l1 - m1) : 0.f;
            pd0 += ev0; pa0 += ev0 * x0s; pb0 += ev0 * x1s;
            pd1 += ev1; pa1 += ev1 * x0s; pb1 += ev1 * x1s;
        }
        pd0 = wredsum(pd0); pa0 = wredsum(pa0); pb0 = wredsum(pb0);
        pd1 = wredsum(pd1); pa1 = wredsum(pa1); pb1 = wredsum(pb1);
        int d = lane, hh = lane >> 5;
        float den = hh ? pd1 : pd0, ta = hh ? pa1 : pa0, tb = hh ? pb1 : pb0;
        float agg = ta * sW[0][d] + tb * sW[1][d] + den * sW[2][d];
        float hv = agg / (den + 1e-16f) + sW[11][d]
                 + x0d * sW[8][d] + x1d * sW[9][d] + sW[10][d];
        hout[(size_t)n * 64 + d] = hv;
        bs += hv; bq += hv * hv;
    }
    sv[threadIdx.x] = bs; sq[threadIdx.x] = bq;
    __syncthreads();
    if (threadIdx.x < 64) {
        float a = sv[threadIdx.x] + sv[threadIdx.x + 64] + sv[threadIdx.x + 128] + sv[threadIdx.x + 192];
        float b = sq[threadIdx.x] + sq[threadIdx.x + 64] + sq[threadIdx.x + 128] + sq[threadIdx.x + 192];
        partial[(size_t)blockIdx.x * 128 + threadIdx.x] = a;
        partial[(size_t)blockIdx.x * 128 + 64 + threadIdx.x] = b;
    }
}

// ---- Kred: reduce per-block BN partials ----
__global__ void kred(const float* __restrict__ partial, float* __restrict__ bnstat, int G) {
    __shared__ float sm[256];
    int c = blockIdx.x;
    float s = 0.f;
    for (int i = threadIdx.x; i < G; i += blockDim.x) s += partial[(size_t)i * 128 + c];
    sm[threadIdx.x] = s;
    __syncthreads();
    for (int off = 128; off >= 1; off >>= 1) {
        if (threadIdx.x < off) sm[threadIdx.x] += sm[threadIdx.x + off];
        __syncthreads();
    }
    if (threadIdx.x == 0) bnstat[c] = sm[0];
}

// ---- K3b: mu, rstd ----
__global__ void k3b(const float* __restrict__ bnsum, const float* __restrict__ bnsq,
                    float* __restrict__ mu, float* __restrict__ rstd, int N) {
    int d = threadIdx.x;
    float m = bnsum[d] / (float)N;
    float v = bnsq[d] / (float)N - m * m;
    mu[d] = m;
    rstd[d] = rsqrtf(v + 1e-5f);
}

// ---- K3c: BN + ELU -> xl2, xr2 (wave per node) ----
__global__ void k3c(const float* __restrict__ h, const float* __restrict__ mu,
                    const float* __restrict__ rstd, const float* __restrict__ gamma,
                    const float* __restrict__ beta,
                    const float* __restrict__ Wl, const float* __restrict__ bl,
                    const float* __restrict__ Wr, const float* __restrict__ br,
                    float* __restrict__ xl2, float* __restrict__ xr2, int N) {
    __shared__ float sh[4][64];
    int w = threadIdx.x >> 6, lane = threadIdx.x & 63;
    int n = blockIdx.x * 4 + w;
    bool valid = (n < N);
    if (valid) {
        float hv = h[(size_t)n * 64 + lane];
        hv = (hv - mu[lane]) * rstd[lane] * gamma[lane] + beta[lane];
        sh[w][lane] = elu1(hv);
    }
    __syncthreads();
    if (!valid) return;
    int c = lane & 31;
    const float* W = (lane < 32) ? Wl : Wr;
    const float* b = (lane < 32) ? bl : br;
    float acc = b[c];
    #pragma unroll
    for (int k = 0; k < 64; ++k) acc += sh[w][k] * W[k * 32 + c];
    ((lane < 32) ? xl2 : xr2)[(size_t)n * 32 + c] = acc;
}

// ---- kL2: layer-2 per-node (wave/node, 2 edges per iter): gather xl2[src],
//      single-pass online softmax, write normalized h2 + alpha. No atomics. ----
__global__ void kL2(const float* __restrict__ xl2, const float* __restrict__ xr2,
                    const int* __restrict__ srcS, const float* __restrict__ eaS,
                    const int* __restrict__ origS,
                    const int* __restrict__ rowstart, const int* __restrict__ cnt,
                    const float* __restrict__ We, const float* __restrict__ att,
                    float* __restrict__ logitS, float* __restrict__ h2,
                    float* __restrict__ alpha, int N) {
    int w = threadIdx.x >> 6, lane = threadIdx.x & 63;
    int half = lane >> 5, c = lane & 31;
    int n = blockIdx.x * 4 + w;
    if (n >= N) return;
    float wev = We[c], attv = att[c];
    int start = rowstart[n], len = cnt[n] + 1;
    float xr2v = xr2[(size_t)n * 32 + c];
    float m = -1e30f, den = 0.f, acc = 0.f;
    int iters = (len + 1) >> 1;
    for (int it = 0; it < iters; ++it) {
        int i = it * 2 + half;
        bool act = i < len;
        int e = start + i;
        float eav = 0.f, xlv = 0.f;
        if (act) {
            int s = srcS[e]; eav = eaS[e];
            xlv = xl2[(size_t)s * 32 + c];
        }
        float mm = xlv + xr2v + eav * wev;
        float p = lrelu(mm) * attv;
        float l = hredsum(p);
        if (!act) l = -1e30f;
        if (l > m) { float r = expf(m - l); den *= r; acc *= r; m = l; }
        float ev = act ? expf(l - m) : 0.f;
        den += ev; acc += ev * xlv;
        if (act && c == 0) logitS[e] = l;
    }
    // combine halves
    float mo = __shfl_xor(m, 32);
    float M = fmaxf(m, mo);
    float r = expf(m - M);
    den *= r; acc *= r;
    den += __shfl_xor(den, 32);
    acc += __shfl_xor(acc, 32);
    float invd = 1.f / (den + 1e-16f);
    if (half == 0) h2[(size_t)n * 32 + c] = acc * invd;
    // alpha pass (logitS just written, L2-hot)
    for (int i = lane; i < len; i += 64) {
        int e = start + i;
        float a = expf(logitS[e] - M) * invd;
        alpha[origS[e]] = a;
    }
}

// ---- K5: h2 -> elu -> two MLP heads -> log_softmax -> out[N,30] ----
__global__ void k5(const float* __restrict__ h2, const float* __restrict__ bias2,
                   const float* __restrict__ Wt1, const float* __restrict__ bt1,
                   const float* __restrict__ Wt2, const float* __restrict__ bt2,
                   const float* __restrict__ Wc1, const float* __restrict__ bc1,
                   const float* __restrict__ Wc2, const float* __restrict__ bc2,
                   float* __restrict__ out, int N) {
    __shared__ float sWt1[1024], sWc1[1024], sWt2[640], sWc2[320];
    __shared__ float sbt1[32], sbc1[32], sbt2[20], sbc2[10], sb2[32];
    for (int i = threadIdx.x; i < 1024; i += blockDim.x) { sWt1[i] = Wt1[i]; sWc1[i] = Wc1[i]; }
    for (int i = threadIdx.x; i < 640; i += blockDim.x) sWt2[i] = Wt2[i];
    for (int i = threadIdx.x; i < 320; i += blockDim.x) sWc2[i] = Wc2[i];
    if (threadIdx.x < 32) { sbt1[threadIdx.x] = bt1[threadIdx.x]; sbc1[threadIdx.x] = bc1[threadIdx.x]; sb2[threadIdx.x] = bias2[threadIdx.x]; }
    if (threadIdx.x < 20) sbt2[threadIdx.x] = bt2[threadIdx.x];
    if (threadIdx.x < 10) sbc2[threadIdx.x] = bc2[threadIdx.x];
    __syncthreads();
    int n = blockIdx.x * blockDim.x + threadIdx.x;
    if (n >= N) return;
    float h[32];
    #pragma unroll
    for (int k = 0; k < 32; ++k) h[k] = elu1(h2[(size_t)n * 32 + k] + sb2[k]);
    float t1[32], c1[32];
    #pragma unroll
    for (int j = 0; j < 32; ++j) {
        float at = sbt1[j], ac = sbc1[j];
        #pragma unroll
        for (int k = 0; k < 32; ++k) { at += h[k] * sWt1[k * 32 + j]; ac += h[k] * sWc1[k * 32 + j]; }
        t1[j] = fmaxf(at, 0.f);
        c1[j] = fmaxf(ac, 0.f);
    }
    float lt[20]; float mt = -1e30f;
    #pragma unroll
    for (int o = 0; o < 20; ++o) {
        float a = sbt2[o];
        #pragma unroll
        for (int k = 0; k < 32; ++k) a += t1[k] * sWt2[k * 20 + o];
        lt[o] = a; mt = fmaxf(mt, a);
    }
    float st = 0.f;
    #pragma unroll
    for (int o = 0; o < 20; ++o) st += expf(lt[o] - mt);
    float lset = mt + logf(st);
    float lc[10]; float mc = -1e30f;
    #pragma unroll
    for (int o = 0; o < 10; ++o) {
        float a = sbc2[o];
        #pragma unroll
        for (int k = 0; k < 32; ++k) a += c1[k] * sWc2[k * 10 + o];
        lc[o] = a; mc = fmaxf(mc, a);
    }
    float sc = 0.f;
    #pragma unroll
    for (int o = 0; o < 10; ++o) sc += expf(lc[o] - mc);
    float lsec = mc + logf(sc);
    #pragma unroll
    for (int o = 0; o < 10; ++o) out[(size_t)n * 30 + o] = lc[o] - lsec;
    #pragma unroll
    for (int o = 0; o < 20; ++o) out[(size_t)n * 30 + 10 + o] = lt[o] - lset;
}

extern "C" void kernel_launch(void* const* d_in, const int* in_sizes, int n_in,
                              void* d_out, int out_size, void* d_ws, size_t ws_size,
                              hipStream_t stream) {
    const float* x     = (const float*)d_in[0];
    const int*   ei    = (const int*)d_in[1];
    const float* eattr = (const float*)d_in[2];
    const float* Wl1   = (const float*)d_in[3];
    const float* bl1   = (const float*)d_in[4];
    const float* Wr1   = (const float*)d_in[5];
    const float* br1   = (const float*)d_in[6];
    const float* We1   = (const float*)d_in[7];
    const float* att1  = (const float*)d_in[8];
    const float* bias1 = (const float*)d_in[9];
    const float* skW   = (const float*)d_in[10];
    const float* skb   = (const float*)d_in[11];
    const float* gamma = (const float*)d_in[12];
    const float* beta  = (const float*)d_in[13];
    const float* Wl2   = (const float*)d_in[14];
    const float* bl2   = (const float*)d_in[15];
    const float* Wr2   = (const float*)d_in[16];
    const float* br2   = (const float*)d_in[17];
    const float* We2   = (const float*)d_in[18];
    const float* att2  = (const float*)d_in[19];
    const float* bias2 = (const float*)d_in[20];
    const float* Wc1   = (const float*)d_in[21];
    const float* bc1   = (const float*)d_in[22];
    const float* Wc2   = (const float*)d_in[23];
    const float* bc2   = (const float*)d_in[24];
    const float* Wt1   = (const float*)d_in[25];
    const float* bt1   = (const float*)d_in[26];
    const float* Wt2   = (const float*)d_in[27];
    const float* bt2   = (const float*)d_in[28];

    const int N  = in_sizes[0] / 2;
    const int E  = in_sizes[1] / 2;
    const int Et = E + N;
    const int* srcA = ei;
    const int* dstA = ei + E;
    const int G1 = 2048;                 // kL1 grid
    const int B  = (N + 255) / 256;      // scan blocks

    // workspace carve
    char* p = (char*)d_ws;
    float* hbuf   = (float*)p; p += (size_t)N * 64 * 4;   // h rows; later h2 (N*32)
    float* xl2    = (float*)p; p += (size_t)N * 32 * 4;
    float* xr2    = (float*)p; p += (size_t)N * 32 * 4;
    float* logitS = (float*)p; p += (size_t)Et * 4;
    int*   srcS   = (int*)p;   p += (size_t)Et * 4;
    float* eaS    = (float*)p; p += (size_t)Et * 4;
    int*   origS  = (int*)p;   p += (size_t)Et * 4;
    int*   cnt    = (int*)p;   p += (size_t)N * 4;        // cnt+cursor+asum contiguous
    int*   cursor = (int*)p;   p += (size_t)N * 4;
    float* asum   = (float*)p; p += (size_t)N * 4;
    int*   rowst  = (int*)p;   p += (size_t)N * 4;
    int*   bsum   = (int*)p;   p += 512 * 4;
    float* partial= (float*)p; p += (size_t)G1 * 128 * 4;
    float* bnstat = (float*)p; p += 128 * 4;
    float* mu     = (float*)p; p += 64 * 4;
    float* rstd   = (float*)p; p += 64 * 4;
    float* h2     = hbuf;  // reuse (hbuf dead after k3c)

    float* outMain  = (float*)d_out;
    float* outAlpha = outMain + (size_t)N * 30;

    // ---- CSR build ----
    hipMemsetAsync(cnt, 0, (size_t)3 * N * 4, stream);    // cnt + cursor + asum
    k0_deg<<<(E + 255) / 256, 256, 0, stream>>>(dstA, eattr, cnt, asum, E);
    kscanA<<<B, 256, 0, stream>>>(cnt, rowst, bsum, N);
    kscanB<<<1, 512, 0, stream>>>(bsum, B);
    kscanC<<<B, 256, 0, stream>>>(rowst, bsum, N);
    kscatter<<<(Et + 255) / 256, 256, 0, stream>>>(srcA, dstA, eattr, asum, cnt, rowst,
                                                   cursor, srcS, eaS, origS, E, Et);

    // ---- layer 1 + skip + BN stats ----
    kL1<<<G1, 256, 0, stream>>>(x, srcS, eaS, rowst, cnt, Wl1, bl1, Wr1, br1, We1, att1,
                                skW, skb, bias1, hbuf, partial, N);
    kred<<<128, 256, 0, stream>>>(partial, bnstat, G1);
    k3b<<<1, 64, 0, stream>>>(bnstat, bnstat + 64, mu, rstd, N);
    k3c<<<(N + 3) / 4, 256, 0, stream>>>(hbuf, mu, rstd, gamma, beta,
                                         Wl2, bl2, Wr2, br2, xl2, xr2, N);

    // ---- layer 2 (fused logits/softmax/agg/alpha, no atomics) ----
    kL2<<<(N + 3) / 4, 256, 0, stream>>>(xl2, xr2, srcS, eaS, origS, rowst, cnt,
                                         We2, att2, logitS, h2, outAlpha, N);

    // ---- heads ----
    k5<<<(N + 255) / 256, 256, 0, stream>>>(h2, bias2, Wt1, bt1, Wt2, bt2,
                                            Wc1, bc1, Wc2, bc2, outMain, N);
    (void)n_in; (void)out_size; (void)ws_size;
}

// Round 4
// 1395.874 us; speedup vs baseline: 2.8378x; 2.8378x over previous
//
#include <hip/hip_runtime.h>
#include <math.h>

#define NEG_SLOPE 0.2f

__device__ __forceinline__ void atomAddF(float* p, float v) {
    unsafeAtomicAdd(p, v);  // HW global_atomic_add_f32
}
__device__ __forceinline__ float lrelu(float x) { return x > 0.f ? x : NEG_SLOPE * x; }
__device__ __forceinline__ float elu1(float x) { return x > 0.f ? x : expf(x) - 1.f; }

__device__ __forceinline__ float hredsum(float v) {  // within 32-lane half
    #pragma unroll
    for (int m = 16; m; m >>= 1) v += __shfl_xor(v, m);
    return v;
}

// ---- K0: in-degree + edge_attr sum per dst (self-loop attr 'mean') ----
__global__ void k0_deg(const int* __restrict__ dst, const float* __restrict__ ea,
                       float* __restrict__ deg, float* __restrict__ asum, int E) {
    int t = blockIdx.x * blockDim.x + threadIdx.x;
    if (t >= E) return;
    int d = dst[t];
    atomAddF(&deg[d], 1.0f);
    atomAddF(&asum[d], ea[t]);
}

// ---- kA: layer-1 fully fused (thread per edge): rank-2 logits -> exp (no max-sub)
//      -> 6 scalar moment atomics per dst. No logit/amax arrays. ----
__global__ void kA(const float* __restrict__ x,
                   const int* __restrict__ srcA, const int* __restrict__ dstA,
                   const float* __restrict__ ea, const float* __restrict__ asum,
                   const float* __restrict__ deg,
                   const float* __restrict__ Wl, const float* __restrict__ bl,
                   const float* __restrict__ Wr, const float* __restrict__ br,
                   const float* __restrict__ We, const float* __restrict__ att,
                   float* __restrict__ dstat, int E, int Et) {
    __shared__ float sW[8][64];  // wl0,wl1,bl,wr0,wr1,br,we,att
    if (threadIdx.x < 64) {
        int d = threadIdx.x;
        sW[0][d] = Wl[d];  sW[1][d] = Wl[64 + d]; sW[2][d] = bl[d];
        sW[3][d] = Wr[d];  sW[4][d] = Wr[64 + d]; sW[5][d] = br[d];
        sW[6][d] = We[d];  sW[7][d] = att[d];
    }
    __syncthreads();
    int t = blockIdx.x * blockDim.x + threadIdx.x;
    if (t >= Et) return;
    int s, d; float eav;
    if (t < E) { s = srcA[t]; d = dstA[t]; eav = ea[t]; }
    else       { s = d = t - E; eav = asum[s] / fmaxf(deg[s], 1.0f); }
    float2 xs = ((const float2*)x)[s];
    float2 xd = ((const float2*)x)[d];
    float l0 = 0.f, l1 = 0.f;
    #pragma unroll
    for (int c = 0; c < 32; ++c) {
        float m0 = xs.x * sW[0][c] + xs.y * sW[1][c] + sW[2][c]
                 + xd.x * sW[3][c] + xd.y * sW[4][c] + sW[5][c] + eav * sW[6][c];
        l0 += lrelu(m0) * sW[7][c];
        int c2 = c + 32;
        float m1 = xs.x * sW[0][c2] + xs.y * sW[1][c2] + sW[2][c2]
                 + xd.x * sW[3][c2] + xd.y * sW[4][c2] + sW[5][c2] + eav * sW[6][c2];
        l1 += lrelu(m1) * sW[7][c2];
    }
    // logits are O(1); exp without max-subtraction is safe in fp32 and
    // softmax is shift-invariant, so downstream alpha/agg are unchanged.
    float ev0 = expf(l0), ev1 = expf(l1);
    float* p = &dstat[(size_t)d * 6];
    atomAddF(p + 0, ev0);         atomAddF(p + 1, ev1);
    atomAddF(p + 2, ev0 * xs.x);  atomAddF(p + 3, ev1 * xs.x);
    atomAddF(p + 4, ev0 * xs.y);  atomAddF(p + 5, ev1 * xs.y);
}

// ---- K3a: reconstruct h = agg/denom + bias1 + skip; BN partials ----
__global__ void k3a(const float* __restrict__ x, const float* __restrict__ dstat,
                    const float* __restrict__ Wl, const float* __restrict__ bl,
                    const float* __restrict__ bias1,
                    const float* __restrict__ skW, const float* __restrict__ skb,
                    float* __restrict__ hout, float* __restrict__ partial, int N) {
    __shared__ float sv[256], sq[256];
    size_t total = (size_t)N * 64;
    size_t stride = (size_t)gridDim.x * blockDim.x;   // multiple of 64 -> d fixed per thread
    float s = 0.f, q = 0.f;
    for (size_t idx = (size_t)blockIdx.x * blockDim.x + threadIdx.x; idx < total; idx += stride) {
        int n = (int)(idx >> 6), d = (int)(idx & 63), h2 = d >> 5;
        const float* ps = &dstat[(size_t)n * 6];
        float den = ps[h2], t0 = ps[2 + h2], t1 = ps[4 + h2];
        float agg = t0 * Wl[d] + t1 * Wl[64 + d] + den * bl[d];
        float hv = agg / (den + 1e-16f) + bias1[d]
                 + x[2 * n] * skW[d] + x[2 * n + 1] * skW[64 + d] + skb[d];
        hout[idx] = hv;
        s += hv; q += hv * hv;
    }
    sv[threadIdx.x] = s; sq[threadIdx.x] = q;
    __syncthreads();
    if (threadIdx.x < 64) {
        float a = sv[threadIdx.x] + sv[threadIdx.x + 64] + sv[threadIdx.x + 128] + sv[threadIdx.x + 192];
        float b = sq[threadIdx.x] + sq[threadIdx.x + 64] + sq[threadIdx.x + 128] + sq[threadIdx.x + 192];
        partial[(size_t)blockIdx.x * 128 + threadIdx.x] = a;
        partial[(size_t)blockIdx.x * 128 + 64 + threadIdx.x] = b;
    }
}

// ---- Kred: reduce per-block BN partials (128 columns) ----
__global__ void kred(const float* __restrict__ partial, float* __restrict__ bnstat, int G) {
    __shared__ float sm[256];
    int c = blockIdx.x;
    float s = 0.f;
    for (int i = threadIdx.x; i < G; i += blockDim.x) s += partial[(size_t)i * 128 + c];
    sm[threadIdx.x] = s;
    __syncthreads();
    for (int off = 128; off >= 1; off >>= 1) {
        if (threadIdx.x < off) sm[threadIdx.x] += sm[threadIdx.x + off];
        __syncthreads();
    }
    if (threadIdx.x == 0) bnstat[c] = sm[0];
}

// ---- K3b: mu, rstd ----
__global__ void k3b(const float* __restrict__ bnsum, const float* __restrict__ bnsq,
                    float* __restrict__ mu, float* __restrict__ rstd, int N) {
    int d = threadIdx.x;
    float m = bnsum[d] / (float)N;
    float v = bnsq[d] / (float)N - m * m;
    mu[d] = m;
    rstd[d] = rsqrtf(v + 1e-5f);
}

// ---- K3c: BN + ELU -> xl2 = h@Wl2+bl2, xr2 = h@Wr2+br2 (wave per node) ----
__global__ void k3c(const float* __restrict__ h, const float* __restrict__ mu,
                    const float* __restrict__ rstd, const float* __restrict__ gamma,
                    const float* __restrict__ beta,
                    const float* __restrict__ Wl, const float* __restrict__ bl,
                    const float* __restrict__ Wr, const float* __restrict__ br,
                    float* __restrict__ xl2, float* __restrict__ xr2, int N) {
    __shared__ float sh[4][64];
    int w = threadIdx.x >> 6, lane = threadIdx.x & 63;
    int n = blockIdx.x * 4 + w;
    bool valid = (n < N);
    if (valid) {
        float hv = h[(size_t)n * 64 + lane];
        hv = (hv - mu[lane]) * rstd[lane] * gamma[lane] + beta[lane];
        sh[w][lane] = elu1(hv);
    }
    __syncthreads();
    if (!valid) return;
    int c = lane & 31;
    const float* W = (lane < 32) ? Wl : Wr;
    const float* b = (lane < 32) ? bl : br;
    float acc = b[c];
    #pragma unroll
    for (int k = 0; k < 64; ++k) acc += sh[w][k] * W[k * 32 + c];
    ((lane < 32) ? xl2 : xr2)[(size_t)n * 32 + c] = acc;
}

// ---- kB: layer-2 fused (2 edges per wave): gather, logit -> ev=exp (no max-sub),
//      store ev, atomics denom + 32-wide agg. Single gather pass. ----
__global__ void kB(const float* __restrict__ xl2, const float* __restrict__ xr2,
                   const int* __restrict__ srcA, const int* __restrict__ dstA,
                   const float* __restrict__ ea, const float* __restrict__ asum,
                   const float* __restrict__ deg,
                   const float* __restrict__ We, const float* __restrict__ att,
                   float* __restrict__ evbuf, float* __restrict__ denom,
                   float* __restrict__ agg, int E, int Et) {
    int t = blockIdx.x * (blockDim.x >> 5) + (threadIdx.x >> 5);
    int c = threadIdx.x & 31;
    if (t >= Et) return;
    int s, d; float eav;
    if (t < E) { s = srcA[t]; d = dstA[t]; eav = ea[t]; }
    else       { s = d = t - E; eav = asum[s] / fmaxf(deg[s], 1.0f); }
    float xlv = xl2[(size_t)s * 32 + c];
    float m = xlv + xr2[(size_t)d * 32 + c] + eav * We[c];
    float p = lrelu(m) * att[c];
    p = hredsum(p);
    float ev = expf(p);
    if (c == 0) { evbuf[t] = ev; atomAddF(&denom[d], ev); }
    atomAddF(&agg[(size_t)d * 32 + c], ev * xlv);
}

// ---- K4c: alpha output ----
__global__ void k4c(const float* __restrict__ evbuf, const int* __restrict__ dstA,
                    const float* __restrict__ denom, float* __restrict__ alpha, int E, int Et) {
    int t = blockIdx.x * blockDim.x + threadIdx.x;
    if (t >= Et) return;
    int d = (t < E) ? dstA[t] : (t - E);
    alpha[t] = evbuf[t] / (denom[d] + 1e-16f);
}

// ---- K5: out2 -> elu -> two MLP heads -> log_softmax -> out[N,30] ----
__global__ void k5(const float* __restrict__ agg, const float* __restrict__ denom,
                   const float* __restrict__ bias2,
                   const float* __restrict__ Wt1, const float* __restrict__ bt1,
                   const float* __restrict__ Wt2, const float* __restrict__ bt2,
                   const float* __restrict__ Wc1, const float* __restrict__ bc1,
                   const float* __restrict__ Wc2, const float* __restrict__ bc2,
                   float* __restrict__ out, int N) {
    __shared__ float sWt1[1024], sWc1[1024], sWt2[640], sWc2[320];
    __shared__ float sbt1[32], sbc1[32], sbt2[20], sbc2[10], sb2[32];
    for (int i = threadIdx.x; i < 1024; i += blockDim.x) { sWt1[i] = Wt1[i]; sWc1[i] = Wc1[i]; }
    for (int i = threadIdx.x; i < 640; i += blockDim.x) sWt2[i] = Wt2[i];
    for (int i = threadIdx.x; i < 320; i += blockDim.x) sWc2[i] = Wc2[i];
    if (threadIdx.x < 32) { sbt1[threadIdx.x] = bt1[threadIdx.x]; sbc1[threadIdx.x] = bc1[threadIdx.x]; sb2[threadIdx.x] = bias2[threadIdx.x]; }
    if (threadIdx.x < 20) sbt2[threadIdx.x] = bt2[threadIdx.x];
    if (threadIdx.x < 10) sbc2[threadIdx.x] = bc2[threadIdx.x];
    __syncthreads();
    int n = blockIdx.x * blockDim.x + threadIdx.x;
    if (n >= N) return;
    float dn = denom[n] + 1e-16f;
    float h[32];
    #pragma unroll
    for (int k = 0; k < 32; ++k) {
        float v = agg[(size_t)n * 32 + k] / dn + sb2[k];
        h[k] = elu1(v);
    }
    float t1[32], c1[32];
    #pragma unroll
    for (int j = 0; j < 32; ++j) {
        float at = sbt1[j], ac = sbc1[j];
        #pragma unroll
        for (int k = 0; k < 32; ++k) { at += h[k] * sWt1[k * 32 + j]; ac += h[k] * sWc1[k * 32 + j]; }
        t1[j] = fmaxf(at, 0.f);
        c1[j] = fmaxf(ac, 0.f);
    }
    float lt[20]; float mt = -1e30f;
    #pragma unroll
    for (int o = 0; o < 20; ++o) {
        float a = sbt2[o];
        #pragma unroll
        for (int k = 0; k < 32; ++k) a += t1[k] * sWt2[k * 20 + o];
        lt[o] = a; mt = fmaxf(mt, a);
    }
    float st = 0.f;
    #pragma unroll
    for (int o = 0; o < 20; ++o) st += expf(lt[o] - mt);
    float lset = mt + logf(st);
    float lc[10]; float mc = -1e30f;
    #pragma unroll
    for (int o = 0; o < 10; ++o) {
        float a = sbc2[o];
        #pragma unroll
        for (int k = 0; k < 32; ++k) a += c1[k] * sWc2[k * 10 + o];
        lc[o] = a; mc = fmaxf(mc, a);
    }
    float sc = 0.f;
    #pragma unroll
    for (int o = 0; o < 10; ++o) sc += expf(lc[o] - mc);
    float lsec = mc + logf(sc);
    #pragma unroll
    for (int o = 0; o < 10; ++o) out[(size_t)n * 30 + o] = lc[o] - lsec;
    #pragma unroll
    for (int o = 0; o < 20; ++o) out[(size_t)n * 30 + 10 + o] = lt[o] - lset;
}

extern "C" void kernel_launch(void* const* d_in, const int* in_sizes, int n_in,
                              void* d_out, int out_size, void* d_ws, size_t ws_size,
                              hipStream_t stream) {
    const float* x     = (const float*)d_in[0];
    const int*   ei    = (const int*)d_in[1];
    const float* eattr = (const float*)d_in[2];
    const float* Wl1   = (const float*)d_in[3];
    const float* bl1   = (const float*)d_in[4];
    const float* Wr1   = (const float*)d_in[5];
    const float* br1   = (const float*)d_in[6];
    const float* We1   = (const float*)d_in[7];
    const float* att1  = (const float*)d_in[8];
    const float* bias1 = (const float*)d_in[9];
    const float* skW   = (const float*)d_in[10];
    const float* skb   = (const float*)d_in[11];
    const float* gamma = (const float*)d_in[12];
    const float* beta  = (const float*)d_in[13];
    const float* Wl2   = (const float*)d_in[14];
    const float* bl2   = (const float*)d_in[15];
    const float* Wr2   = (const float*)d_in[16];
    const float* br2   = (const float*)d_in[17];
    const float* We2   = (const float*)d_in[18];
    const float* att2  = (const float*)d_in[19];
    const float* bias2 = (const float*)d_in[20];
    const float* Wc1   = (const float*)d_in[21];
    const float* bc1   = (const float*)d_in[22];
    const float* Wc2   = (const float*)d_in[23];
    const float* bc2   = (const float*)d_in[24];
    const float* Wt1   = (const float*)d_in[25];
    const float* bt1   = (const float*)d_in[26];
    const float* Wt2   = (const float*)d_in[27];
    const float* bt2   = (const float*)d_in[28];

    const int N  = in_sizes[0] / 2;
    const int E  = in_sizes[1] / 2;
    const int Et = E + N;
    const int* srcA = ei;
    const int* dstA = ei + E;
    const int G3 = 1024;

    // workspace layout (floats)
    float* w = (float*)d_ws;
    float* hbuf   = w; w += (size_t)N * 64;
    float* xl2    = w; w += (size_t)N * 32;
    float* xr2    = w; w += (size_t)N * 32;
    float* agg2   = w; w += (size_t)N * 32;   // agg2 + denom2 contiguous for one memset
    float* denom2 = w; w += N;
    float* evbuf  = w; w += Et;
    float* dstat  = w; w += (size_t)6 * N;
    float* deg    = w; w += N;                // deg + asum contiguous
    float* asum   = w; w += N;
    float* partial= w; w += (size_t)G3 * 128;
    float* bnstat = w; w += 128;
    float* mu     = w; w += 64;
    float* rstd   = w; w += 64;

    float* outMain  = (float*)d_out;
    float* outAlpha = outMain + (size_t)N * 30;

    // ---- self-loop attr prep ----
    hipMemsetAsync(deg, 0, (size_t)2 * N * sizeof(float), stream);   // deg + asum
    k0_deg<<<(E + 255) / 256, 256, 0, stream>>>(dstA, eattr, deg, asum, E);

    // ---- layer 1 (single fused edge pass) ----
    hipMemsetAsync(dstat, 0, (size_t)6 * N * sizeof(float), stream);
    kA<<<(Et + 255) / 256, 256, 0, stream>>>(x, srcA, dstA, eattr, asum, deg,
                                             Wl1, bl1, Wr1, br1, We1, att1,
                                             dstat, E, Et);

    // ---- node reconstruction + skip + BN ----
    k3a<<<G3, 256, 0, stream>>>(x, dstat, Wl1, bl1, bias1, skW, skb, hbuf, partial, N);
    kred<<<128, 256, 0, stream>>>(partial, bnstat, G3);
    k3b<<<1, 64, 0, stream>>>(bnstat, bnstat + 64, mu, rstd, N);
    k3c<<<(N + 3) / 4, 256, 0, stream>>>(hbuf, mu, rstd, gamma, beta,
                                         Wl2, bl2, Wr2, br2, xl2, xr2, N);

    // ---- layer 2 (single fused edge pass) ----
    hipMemsetAsync(agg2, 0, (size_t)N * 33 * sizeof(float), stream);  // agg2 + denom2
    kB<<<(Et + 7) / 8, 256, 0, stream>>>(xl2, xr2, srcA, dstA, eattr, asum, deg,
                                         We2, att2, evbuf, denom2, agg2, E, Et);
    k4c<<<(Et + 255) / 256, 256, 0, stream>>>(evbuf, dstA, denom2, outAlpha, E, Et);

    // ---- heads ----
    k5<<<(N + 255) / 256, 256, 0, stream>>>(agg2, denom2, bias2, Wt1, bt1, Wt2, bt2,
                                            Wc1, bc1, Wc2, bc2, outMain, N);
    (void)n_in; (void)out_size; (void)ws_size;
}

// Round 5
// 1126.283 us; speedup vs baseline: 3.5170x; 1.2394x over previous
//
#include <hip/hip_runtime.h>
#include <math.h>

#define NEG_SLOPE 0.2f
#define CNT_SHIFT 44
#define EA_SCALE 262144.0f          // 2^18 fixed-point for edge_attr sums
#define EA_INV (1.0f / 262144.0f)

__device__ __forceinline__ float lrelu(float x) { return x > 0.f ? x : NEG_SLOPE * x; }
__device__ __forceinline__ float elu1(float x) { return x > 0.f ? x : expf(x) - 1.f; }

__device__ __forceinline__ float hredsum(float v) {  // reduce within 32-lane half
    #pragma unroll
    for (int m = 16; m; m >>= 1) v += __shfl_xor(v, m);
    return v;
}

// ---- k0p: one u64 atomic per edge: packed[d] += (1<<44) | fix18(ea) ----
__global__ void k0p(const int* __restrict__ dst, const float* __restrict__ ea,
                    unsigned long long* __restrict__ packed, int E) {
    int t = blockIdx.x * blockDim.x + threadIdx.x;
    if (t >= E) return;
    int d = dst[t];
    unsigned long long inc = (1ULL << CNT_SHIFT)
                           | (unsigned long long)__float2uint_rn(ea[t] * EA_SCALE);
    atomicAdd(&packed[d], inc);
}

// ---- kscanA: per-block inclusive scan of (cnt[i]+1); unpack cnt/asum ----
__global__ void kscanA(const unsigned long long* __restrict__ packed,
                       int* __restrict__ rowstart, int* __restrict__ bsum,
                       int* __restrict__ cntA, float* __restrict__ asumA, int N) {
    __shared__ int sm[256];
    int t = threadIdx.x;
    int i = blockIdx.x * 256 + t;
    int v = 0;
    if (i < N) {
        unsigned long long p = packed[i];
        int c = (int)(p >> CNT_SHIFT);
        cntA[i] = c;
        asumA[i] = (float)(p & ((1ULL << CNT_SHIFT) - 1)) * EA_INV;
        v = c + 1;
    }
    sm[t] = v;
    __syncthreads();
    for (int off = 1; off < 256; off <<= 1) {
        int u = (t >= off) ? sm[t - off] : 0;
        __syncthreads();
        sm[t] += u;
        __syncthreads();
    }
    if (i < N) rowstart[i] = sm[t] - v;
    if (t == 255) bsum[blockIdx.x] = sm[255];
}

__global__ void kscanB(int* __restrict__ bsum, int B) {
    __shared__ int sm[512];
    int t = threadIdx.x;
    int v = (t < B) ? bsum[t] : 0;
    sm[t] = v;
    __syncthreads();
    for (int off = 1; off < 512; off <<= 1) {
        int u = (t >= off) ? sm[t - off] : 0;
        __syncthreads();
        sm[t] += u;
        __syncthreads();
    }
    if (t < B) bsum[t] = sm[t] - v;  // exclusive block offsets
}

__global__ void kscanC(int* __restrict__ rowstart, const int* __restrict__ bsum, int N) {
    int i = blockIdx.x * blockDim.x + threadIdx.x;
    if (i < N) rowstart[i] += bsum[i >> 8];
}

// ---- kscatter: edgeS[pos] = {src, ea_bits, orig, 0}; self-loop slot = cnt[d], no atomic ----
__global__ void kscatter(const int* __restrict__ srcA, const int* __restrict__ dstA,
                         const float* __restrict__ ea, const float* __restrict__ asumA,
                         const int* __restrict__ cntA, const int* __restrict__ rowstart,
                         int* __restrict__ cursor, int4* __restrict__ edgeS, int E, int Et) {
    int t = blockIdx.x * blockDim.x + threadIdx.x;
    if (t >= Et) return;
    if (t < E) {
        int d = dstA[t];
        int c = atomicAdd(&cursor[d], 1);
        int cd = cntA[d];
        int pos = rowstart[d] + min(c, cd - 1);   // clamp keeps replays in-range
        edgeS[pos] = make_int4(srcA[t], __float_as_int(ea[t]), t, 0);
    } else {
        int d = t - E;
        int cd = cntA[d];
        int pos = rowstart[d] + cd;
        float eav = asumA[d] / fmaxf((float)cd, 1.0f);
        edgeS[pos] = make_int4(d, __float_as_int(eav), t, 0);
    }
}

// ---- kL1: one THREAD per (node, head): gather edges, rank-2 logits, exp
//      (no max-sub; logits O(1)), accumulate 3 moments in registers. No atomics. ----
__global__ void kL1(const float* __restrict__ x, const int4* __restrict__ edgeS,
                    const int* __restrict__ rowst, const int* __restrict__ cntA,
                    const float* __restrict__ Wl, const float* __restrict__ bl,
                    const float* __restrict__ Wr, const float* __restrict__ br,
                    const float* __restrict__ We, const float* __restrict__ att,
                    float* __restrict__ dstat, int N) {
    __shared__ float sW[7][64];  // wl0, wl1, we, att, wr0, wr1, (bl+br)
    if (threadIdx.x < 64) {
        int d = threadIdx.x;
        sW[0][d] = Wl[d];  sW[1][d] = Wl[64 + d];
        sW[2][d] = We[d];  sW[3][d] = att[d];
        sW[4][d] = Wr[d];  sW[5][d] = Wr[64 + d];
        sW[6][d] = bl[d] + br[d];
    }
    __syncthreads();
    int tid = blockIdx.x * blockDim.x + threadIdx.x;
    int n = tid >> 1, h = tid & 1;
    if (n >= N) return;
    int base = h * 32;
    float2 xd = ((const float2*)x)[n];
    float dstp[32];
    #pragma unroll
    for (int c = 0; c < 32; ++c) {
        int dc = base + c;
        dstp[c] = xd.x * sW[4][dc] + xd.y * sW[5][dc] + sW[6][dc];
    }
    int start = rowst[n], len = cntA[n] + 1;
    float pd = 0.f, pa = 0.f, pb = 0.f;
    for (int i = 0; i < len; ++i) {
        int4 e4 = edgeS[start + i];
        float2 xs = ((const float2*)x)[e4.x];
        float eav = __int_as_float(e4.y);
        float l = 0.f;
        #pragma unroll
        for (int c = 0; c < 32; ++c) {
            int dc = base + c;
            float m = dstp[c] + xs.x * sW[0][dc] + xs.y * sW[1][dc] + eav * sW[2][dc];
            l += lrelu(m) * sW[3][dc];
        }
        float ev = expf(l);
        pd += ev; pa += ev * xs.x; pb += ev * xs.y;
    }
    dstat[(size_t)n * 6 + h]     = pd;
    dstat[(size_t)n * 6 + 2 + h] = pa;
    dstat[(size_t)n * 6 + 4 + h] = pb;
}

// ---- k3a: reconstruct h = agg/denom + bias1 + skip; BN partials ----
__global__ void k3a(const float* __restrict__ x, const float* __restrict__ dstat,
                    const float* __restrict__ Wl, const float* __restrict__ bl,
                    const float* __restrict__ bias1,
                    const float* __restrict__ skW, const float* __restrict__ skb,
                    float* __restrict__ hout, float* __restrict__ partial, int N) {
    __shared__ float sv[256], sq[256];
    size_t total = (size_t)N * 64;
    size_t stride = (size_t)gridDim.x * blockDim.x;
    float s = 0.f, q = 0.f;
    for (size_t idx = (size_t)blockIdx.x * blockDim.x + threadIdx.x; idx < total; idx += stride) {
        int n = (int)(idx >> 6), d = (int)(idx & 63), h2 = d >> 5;
        const float* ps = &dstat[(size_t)n * 6];
        float den = ps[h2], t0 = ps[2 + h2], t1 = ps[4 + h2];
        float agg = t0 * Wl[d] + t1 * Wl[64 + d] + den * bl[d];
        float hv = agg / (den + 1e-16f) + bias1[d]
                 + x[2 * n] * skW[d] + x[2 * n + 1] * skW[64 + d] + skb[d];
        hout[idx] = hv;
        s += hv; q += hv * hv;
    }
    sv[threadIdx.x] = s; sq[threadIdx.x] = q;
    __syncthreads();
    if (threadIdx.x < 64) {
        float a = sv[threadIdx.x] + sv[threadIdx.x + 64] + sv[threadIdx.x + 128] + sv[threadIdx.x + 192];
        float b = sq[threadIdx.x] + sq[threadIdx.x + 64] + sq[threadIdx.x + 128] + sq[threadIdx.x + 192];
        partial[(size_t)blockIdx.x * 128 + threadIdx.x] = a;
        partial[(size_t)blockIdx.x * 128 + 64 + threadIdx.x] = b;
    }
}

// ---- Kred: reduce per-block BN partials ----
__global__ void kred(const float* __restrict__ partial, float* __restrict__ bnstat, int G) {
    __shared__ float sm[256];
    int c = blockIdx.x;
    float s = 0.f;
    for (int i = threadIdx.x; i < G; i += blockDim.x) s += partial[(size_t)i * 128 + c];
    sm[threadIdx.x] = s;
    __syncthreads();
    for (int off = 128; off >= 1; off >>= 1) {
        if (threadIdx.x < off) sm[threadIdx.x] += sm[threadIdx.x + off];
        __syncthreads();
    }
    if (threadIdx.x == 0) bnstat[c] = sm[0];
}

// ---- k3b: mu, rstd ----
__global__ void k3b(const float* __restrict__ bnsum, const float* __restrict__ bnsq,
                    float* __restrict__ mu, float* __restrict__ rstd, int N) {
    int d = threadIdx.x;
    float m = bnsum[d] / (float)N;
    float v = bnsq[d] / (float)N - m * m;
    mu[d] = m;
    rstd[d] = rsqrtf(v + 1e-5f);
}

// ---- k3c: BN + ELU -> xl2, xr2 (wave per node) ----
__global__ void k3c(const float* __restrict__ h, const float* __restrict__ mu,
                    const float* __restrict__ rstd, const float* __restrict__ gamma,
                    const float* __restrict__ beta,
                    const float* __restrict__ Wl, const float* __restrict__ bl,
                    const float* __restrict__ Wr, const float* __restrict__ br,
                    float* __restrict__ xl2, float* __restrict__ xr2, int N) {
    __shared__ float sh[4][64];
    int w = threadIdx.x >> 6, lane = threadIdx.x & 63;
    int n = blockIdx.x * 4 + w;
    bool valid = (n < N);
    if (valid) {
        float hv = h[(size_t)n * 64 + lane];
        hv = (hv - mu[lane]) * rstd[lane] * gamma[lane] + beta[lane];
        sh[w][lane] = elu1(hv);
    }
    __syncthreads();
    if (!valid) return;
    int c = lane & 31;
    const float* W = (lane < 32) ? Wl : Wr;
    const float* b = (lane < 32) ? bl : br;
    float acc = b[c];
    #pragma unroll
    for (int k = 0; k < 64; ++k) acc += sh[w][k] * W[k * 32 + c];
    ((lane < 32) ? xl2 : xr2)[(size_t)n * 32 + c] = acc;
}

// ---- kL2: 32 lanes per node: gather xl2[src] rows, single-pass softmax-sum
//      (no max-sub), write normalized h2 + denom + evbuf[orig]. No atomics. ----
__global__ void kL2(const float* __restrict__ xl2, const float* __restrict__ xr2,
                    const int4* __restrict__ edgeS,
                    const int* __restrict__ rowst, const int* __restrict__ cntA,
                    const float* __restrict__ We, const float* __restrict__ att,
                    float* __restrict__ evbuf, float* __restrict__ h2,
                    float* __restrict__ denom2, int N) {
    int g = blockIdx.x * blockDim.x + threadIdx.x;
    int n = g >> 5, c = g & 31;
    if (n >= N) return;
    float wev = We[c], attv = att[c];
    float xrv = xr2[(size_t)n * 32 + c];
    int start = rowst[n], len = cntA[n] + 1;
    float den = 0.f, acc = 0.f;
    for (int i = 0; i < len; ++i) {
        int4 e4 = edgeS[start + i];
        float eav = __int_as_float(e4.y);
        float xlv = xl2[(size_t)e4.x * 32 + c];
        float p = lrelu(xlv + xrv + eav * wev) * attv;
        float l = hredsum(p);
        float ev = expf(l);
        den += ev; acc += ev * xlv;
        if (c == 0) evbuf[e4.z] = ev;
    }
    float inv = 1.f / (den + 1e-16f);
    h2[(size_t)n * 32 + c] = acc * inv;
    if (c == 0) denom2[n] = den;
}

// ---- k4c: alpha output (original edge order, coalesced) ----
__global__ void k4c(const float* __restrict__ evbuf, const int* __restrict__ dstA,
                    const float* __restrict__ denom, float* __restrict__ alpha, int E, int Et) {
    int t = blockIdx.x * blockDim.x + threadIdx.x;
    if (t >= Et) return;
    int d = (t < E) ? dstA[t] : (t - E);
    alpha[t] = evbuf[t] / (denom[d] + 1e-16f);
}

// ---- k5: h2 -> +bias2 -> elu -> two MLP heads -> log_softmax -> out[N,30] ----
__global__ void k5(const float* __restrict__ h2, const float* __restrict__ bias2,
                   const float* __restrict__ Wt1, const float* __restrict__ bt1,
                   const float* __restrict__ Wt2, const float* __restrict__ bt2,
                   const float* __restrict__ Wc1, const float* __restrict__ bc1,
                   const float* __restrict__ Wc2, const float* __restrict__ bc2,
                   float* __restrict__ out, int N) {
    __shared__ float sWt1[1024], sWc1[1024], sWt2[640], sWc2[320];
    __shared__ float sbt1[32], sbc1[32], sbt2[20], sbc2[10], sb2[32];
    for (int i = threadIdx.x; i < 1024; i += blockDim.x) { sWt1[i] = Wt1[i]; sWc1[i] = Wc1[i]; }
    for (int i = threadIdx.x; i < 640; i += blockDim.x) sWt2[i] = Wt2[i];
    for (int i = threadIdx.x; i < 320; i += blockDim.x) sWc2[i] = Wc2[i];
    if (threadIdx.x < 32) { sbt1[threadIdx.x] = bt1[threadIdx.x]; sbc1[threadIdx.x] = bc1[threadIdx.x]; sb2[threadIdx.x] = bias2[threadIdx.x]; }
    if (threadIdx.x < 20) sbt2[threadIdx.x] = bt2[threadIdx.x];
    if (threadIdx.x < 10) sbc2[threadIdx.x] = bc2[threadIdx.x];
    __syncthreads();
    int n = blockIdx.x * blockDim.x + threadIdx.x;
    if (n >= N) return;
    float h[32];
    #pragma unroll
    for (int k = 0; k < 32; ++k) h[k] = elu1(h2[(size_t)n * 32 + k] + sb2[k]);
    float t1[32], c1[32];
    #pragma unroll
    for (int j = 0; j < 32; ++j) {
        float at = sbt1[j], ac = sbc1[j];
        #pragma unroll
        for (int k = 0; k < 32; ++k) { at += h[k] * sWt1[k * 32 + j]; ac += h[k] * sWc1[k * 32 + j]; }
        t1[j] = fmaxf(at, 0.f);
        c1[j] = fmaxf(ac, 0.f);
    }
    float lt[20]; float mt = -1e30f;
    #pragma unroll
    for (int o = 0; o < 20; ++o) {
        float a = sbt2[o];
        #pragma unroll
        for (int k = 0; k < 32; ++k) a += t1[k] * sWt2[k * 20 + o];
        lt[o] = a; mt = fmaxf(mt, a);
    }
    float st = 0.f;
    #pragma unroll
    for (int o = 0; o < 20; ++o) st += expf(lt[o] - mt);
    float lset = mt + logf(st);
    float lc[10]; float mc = -1e30f;
    #pragma unroll
    for (int o = 0; o < 10; ++o) {
        float a = sbc2[o];
        #pragma unroll
        for (int k = 0; k < 32; ++k) a += c1[k] * sWc2[k * 10 + o];
        lc[o] = a; mc = fmaxf(mc, a);
    }
    float sc = 0.f;
    #pragma unroll
    for (int o = 0; o < 10; ++o) sc += expf(lc[o] - mc);
    float lsec = mc + logf(sc);
    #pragma unroll
    for (int o = 0; o < 10; ++o) out[(size_t)n * 30 + o] = lc[o] - lsec;
    #pragma unroll
    for (int o = 0; o < 20; ++o) out[(size_t)n * 30 + 10 + o] = lt[o] - lset;
}

extern "C" void kernel_launch(void* const* d_in, const int* in_sizes, int n_in,
                              void* d_out, int out_size, void* d_ws, size_t ws_size,
                              hipStream_t stream) {
    const float* x     = (const float*)d_in[0];
    const int*   ei    = (const int*)d_in[1];
    const float* eattr = (const float*)d_in[2];
    const float* Wl1   = (const float*)d_in[3];
    const float* bl1   = (const float*)d_in[4];
    const float* Wr1   = (const float*)d_in[5];
    const float* br1   = (const float*)d_in[6];
    const float* We1   = (const float*)d_in[7];
    const float* att1  = (const float*)d_in[8];
    const float* bias1 = (const float*)d_in[9];
    const float* skW   = (const float*)d_in[10];
    const float* skb   = (const float*)d_in[11];
    const float* gamma = (const float*)d_in[12];
    const float* beta  = (const float*)d_in[13];
    const float* Wl2   = (const float*)d_in[14];
    const float* bl2   = (const float*)d_in[15];
    const float* Wr2   = (const float*)d_in[16];
    const float* br2   = (const float*)d_in[17];
    const float* We2   = (const float*)d_in[18];
    const float* att2  = (const float*)d_in[19];
    const float* bias2 = (const float*)d_in[20];
    const float* Wc1   = (const float*)d_in[21];
    const float* bc1   = (const float*)d_in[22];
    const float* Wc2   = (const float*)d_in[23];
    const float* bc2   = (const float*)d_in[24];
    const float* Wt1   = (const float*)d_in[25];
    const float* bt1   = (const float*)d_in[26];
    const float* Wt2   = (const float*)d_in[27];
    const float* bt2   = (const float*)d_in[28];

    const int N  = in_sizes[0] / 2;
    const int E  = in_sizes[1] / 2;
    const int Et = E + N;
    const int* srcA = ei;
    const int* dstA = ei + E;
    const int G3 = 1024;
    const int B  = (N + 255) / 256;

    // workspace carve (packed|cursor first: one memset; edgeS before big float
    // buffers so a hypothetical replay-overflow lands in recomputed scratch)
    char* p = (char*)d_ws;
    unsigned long long* packed = (unsigned long long*)p; p += (size_t)N * 8;
    int*   cursor = (int*)p;   p += (size_t)N * 4;
    int4*  edgeS  = (int4*)p;  p += (size_t)Et * 16;
    float* hbuf   = (float*)p; p += (size_t)N * 64 * 4;   // h rows; reused as h2 (N*32)
    float* xl2    = (float*)p; p += (size_t)N * 32 * 4;
    float* xr2    = (float*)p; p += (size_t)N * 32 * 4;
    float* evbuf  = (float*)p; p += (size_t)Et * 4;
    float* dstat  = (float*)p; p += (size_t)N * 6 * 4;
    int*   cntA   = (int*)p;   p += (size_t)N * 4;
    float* asumA  = (float*)p; p += (size_t)N * 4;
    int*   rowst  = (int*)p;   p += (size_t)N * 4;
    int*   bsum   = (int*)p;   p += 512 * 4;
    float* partial= (float*)p; p += (size_t)G3 * 128 * 4;
    float* bnstat = (float*)p; p += 128 * 4;
    float* mu     = (float*)p; p += 64 * 4;
    float* rstd   = (float*)p; p += 64 * 4;
    float* denom2 = (float*)p; p += (size_t)N * 4;
    float* h2     = hbuf;

    float* outMain  = (float*)d_out;
    float* outAlpha = outMain + (size_t)N * 30;

    // ---- CSR build (atomic-light) ----
    hipMemsetAsync(packed, 0, (size_t)N * 12, stream);    // packed + cursor
    k0p<<<(E + 255) / 256, 256, 0, stream>>>(dstA, eattr, packed, E);
    kscanA<<<B, 256, 0, stream>>>(packed, rowst, bsum, cntA, asumA, N);
    kscanB<<<1, 512, 0, stream>>>(bsum, B);
    kscanC<<<B, 256, 0, stream>>>(rowst, bsum, N);
    kscatter<<<(Et + 255) / 256, 256, 0, stream>>>(srcA, dstA, eattr, asumA, cntA,
                                                   rowst, cursor, edgeS, E, Et);

    // ---- layer 1 (gather, zero atomics) ----
    kL1<<<((size_t)2 * N + 255) / 256, 256, 0, stream>>>(x, edgeS, rowst, cntA,
                                                         Wl1, bl1, Wr1, br1, We1, att1,
                                                         dstat, N);

    // ---- node reconstruction + skip + BN ----
    k3a<<<G3, 256, 0, stream>>>(x, dstat, Wl1, bl1, bias1, skW, skb, hbuf, partial, N);
    kred<<<128, 256, 0, stream>>>(partial, bnstat, G3);
    k3b<<<1, 64, 0, stream>>>(bnstat, bnstat + 64, mu, rstd, N);
    k3c<<<(N + 3) / 4, 256, 0, stream>>>(hbuf, mu, rstd, gamma, beta,
                                         Wl2, bl2, Wr2, br2, xl2, xr2, N);

    // ---- layer 2 (gather, zero atomics) ----
    kL2<<<((size_t)N * 32 + 255) / 256, 256, 0, stream>>>(xl2, xr2, edgeS, rowst, cntA,
                                                          We2, att2, evbuf, h2, denom2, N);
    k4c<<<(Et + 255) / 256, 256, 0, stream>>>(evbuf, dstA, denom2, outAlpha, E, Et);

    // ---- heads ----
    k5<<<(N + 255) / 256, 256, 0, stream>>>(h2, bias2, Wt1, bt1, Wt2, bt2,
                                            Wc1, bc1, Wc2, bc2, outMain, N);
    (void)n_in; (void)out_size; (void)ws_size;
}

// Round 6
// 746.578 us; speedup vs baseline: 5.3058x; 1.5086x over previous
//
#include <hip/hip_runtime.h>
#include <math.h>

#define NEG_SLOPE 0.2f
#define CNT_SHIFT 44
#define EA_SCALE 262144.0f          // 2^18 fixed-point for edge_attr sums
#define EA_INV (1.0f / 262144.0f)

__device__ __forceinline__ float lrelu(float x) { return x > 0.f ? x : NEG_SLOPE * x; }
__device__ __forceinline__ float elu1(float x) { return x > 0.f ? x : expf(x) - 1.f; }

__device__ __forceinline__ float hredsum(float v) {  // reduce within 32-lane half
    #pragma unroll
    for (int m = 16; m; m >>= 1) v += __shfl_xor(v, m);
    return v;
}

// ---- k0p: one u64 atomic per edge: packed[d] += (1<<44) | fix18(ea) ----
__global__ void k0p(const int* __restrict__ dst, const float* __restrict__ ea,
                    unsigned long long* __restrict__ packed, int E) {
    int t = blockIdx.x * blockDim.x + threadIdx.x;
    if (t >= E) return;
    int d = dst[t];
    unsigned long long inc = (1ULL << CNT_SHIFT)
                           | (unsigned long long)__float2uint_rn(ea[t] * EA_SCALE);
    atomicAdd(&packed[d], inc);
}

// ---- kscanA: per-block inclusive scan of (cnt[i]+1); unpack cnt/asum ----
__global__ void kscanA(const unsigned long long* __restrict__ packed,
                       int* __restrict__ rowstart, int* __restrict__ bsum,
                       int* __restrict__ cntA, float* __restrict__ asumA, int N) {
    __shared__ int sm[256];
    int t = threadIdx.x;
    int i = blockIdx.x * 256 + t;
    int v = 0;
    if (i < N) {
        unsigned long long p = packed[i];
        int c = (int)(p >> CNT_SHIFT);
        cntA[i] = c;
        asumA[i] = (float)(p & ((1ULL << CNT_SHIFT) - 1)) * EA_INV;
        v = c + 1;
    }
    sm[t] = v;
    __syncthreads();
    for (int off = 1; off < 256; off <<= 1) {
        int u = (t >= off) ? sm[t - off] : 0;
        __syncthreads();
        sm[t] += u;
        __syncthreads();
    }
    if (i < N) rowstart[i] = sm[t] - v;
    if (t == 255) bsum[blockIdx.x] = sm[255];
}

__global__ void kscanB(int* __restrict__ bsum, int B) {
    __shared__ int sm[512];
    int t = threadIdx.x;
    int v = (t < B) ? bsum[t] : 0;
    sm[t] = v;
    __syncthreads();
    for (int off = 1; off < 512; off <<= 1) {
        int u = (t >= off) ? sm[t - off] : 0;
        __syncthreads();
        sm[t] += u;
        __syncthreads();
    }
    if (t < B) bsum[t] = sm[t] - v;  // exclusive block offsets
}

__global__ void kscanC(int* __restrict__ rowstart, const int* __restrict__ bsum, int N) {
    int i = blockIdx.x * blockDim.x + threadIdx.x;
    if (i < N) rowstart[i] += bsum[i >> 8];
}

// ---- kscatter: edgeS[pos] = {src, ea_bits, orig, 0}; self-loop slot = cnt[d], no atomic ----
__global__ void kscatter(const int* __restrict__ srcA, const int* __restrict__ dstA,
                         const float* __restrict__ ea, const float* __restrict__ asumA,
                         const int* __restrict__ cntA, const int* __restrict__ rowstart,
                         int* __restrict__ cursor, int4* __restrict__ edgeS, int E, int Et) {
    int t = blockIdx.x * blockDim.x + threadIdx.x;
    if (t >= Et) return;
    if (t < E) {
        int d = dstA[t];
        int c = atomicAdd(&cursor[d], 1);
        int cd = cntA[d];
        int pos = rowstart[d] + min(c, cd - 1);   // clamp keeps replays in-range
        edgeS[pos] = make_int4(srcA[t], __float_as_int(ea[t]), t, 0);
    } else {
        int d = t - E;
        int cd = cntA[d];
        int pos = rowstart[d] + cd;
        float eav = asumA[d] / fmaxf((float)cd, 1.0f);
        edgeS[pos] = make_int4(d, __float_as_int(eav), t, 0);
    }
}

// ---- kL1: one THREAD per (node, head): gather edges, rank-2 logits, exp
//      (no max-sub; logits O(1)), accumulate 3 moments in registers. No atomics. ----
__global__ void kL1(const float* __restrict__ x, const int4* __restrict__ edgeS,
                    const int* __restrict__ rowst, const int* __restrict__ cntA,
                    const float* __restrict__ Wl, const float* __restrict__ bl,
                    const float* __restrict__ Wr, const float* __restrict__ br,
                    const float* __restrict__ We, const float* __restrict__ att,
                    float* __restrict__ dstat, int N) {
    __shared__ float sW[7][64];  // wl0, wl1, we, att, wr0, wr1, (bl+br)
    if (threadIdx.x < 64) {
        int d = threadIdx.x;
        sW[0][d] = Wl[d];  sW[1][d] = Wl[64 + d];
        sW[2][d] = We[d];  sW[3][d] = att[d];
        sW[4][d] = Wr[d];  sW[5][d] = Wr[64 + d];
        sW[6][d] = bl[d] + br[d];
    }
    __syncthreads();
    int tid = blockIdx.x * blockDim.x + threadIdx.x;
    int n = tid >> 1, h = tid & 1;
    if (n >= N) return;
    int base = h * 32;
    float2 xd = ((const float2*)x)[n];
    float dstp[32];
    #pragma unroll
    for (int c = 0; c < 32; ++c) {
        int dc = base + c;
        dstp[c] = xd.x * sW[4][dc] + xd.y * sW[5][dc] + sW[6][dc];
    }
    int start = rowst[n], len = cntA[n] + 1;
    float pd = 0.f, pa = 0.f, pb = 0.f;
    for (int i = 0; i < len; ++i) {
        int4 e4 = edgeS[start + i];
        float2 xs = ((const float2*)x)[e4.x];
        float eav = __int_as_float(e4.y);
        float l = 0.f;
        #pragma unroll
        for (int c = 0; c < 32; ++c) {
            int dc = base + c;
            float m = dstp[c] + xs.x * sW[0][dc] + xs.y * sW[1][dc] + eav * sW[2][dc];
            l += lrelu(m) * sW[3][dc];
        }
        float ev = expf(l);
        pd += ev; pa += ev * xs.x; pb += ev * xs.y;
    }
    dstat[(size_t)n * 6 + h]     = pd;
    dstat[(size_t)n * 6 + 2 + h] = pa;
    dstat[(size_t)n * 6 + 4 + h] = pb;
}

// ---- k3a: reconstruct h = agg/denom + bias1 + skip; BN partials ----
__global__ void k3a(const float* __restrict__ x, const float* __restrict__ dstat,
                    const float* __restrict__ Wl, const float* __restrict__ bl,
                    const float* __restrict__ bias1,
                    const float* __restrict__ skW, const float* __restrict__ skb,
                    float* __restrict__ hout, float* __restrict__ partial, int N) {
    __shared__ float sv[256], sq[256];
    size_t total = (size_t)N * 64;
    size_t stride = (size_t)gridDim.x * blockDim.x;
    float s = 0.f, q = 0.f;
    for (size_t idx = (size_t)blockIdx.x * blockDim.x + threadIdx.x; idx < total; idx += stride) {
        int n = (int)(idx >> 6), d = (int)(idx & 63), h2 = d >> 5;
        const float* ps = &dstat[(size_t)n * 6];
        float den = ps[h2], t0 = ps[2 + h2], t1 = ps[4 + h2];
        float agg = t0 * Wl[d] + t1 * Wl[64 + d] + den * bl[d];
        float hv = agg / (den + 1e-16f) + bias1[d]
                 + x[2 * n] * skW[d] + x[2 * n + 1] * skW[64 + d] + skb[d];
        hout[idx] = hv;
        s += hv; q += hv * hv;
    }
    sv[threadIdx.x] = s; sq[threadIdx.x] = q;
    __syncthreads();
    if (threadIdx.x < 64) {
        float a = sv[threadIdx.x] + sv[threadIdx.x + 64] + sv[threadIdx.x + 128] + sv[threadIdx.x + 192];
        float b = sq[threadIdx.x] + sq[threadIdx.x + 64] + sq[threadIdx.x + 128] + sq[threadIdx.x + 192];
        partial[(size_t)blockIdx.x * 128 + threadIdx.x] = a;
        partial[(size_t)blockIdx.x * 128 + 64 + threadIdx.x] = b;
    }
}

// ---- Kred: reduce per-block BN partials ----
__global__ void kred(const float* __restrict__ partial, float* __restrict__ bnstat, int G) {
    __shared__ float sm[256];
    int c = blockIdx.x;
    float s = 0.f;
    for (int i = threadIdx.x; i < G; i += blockDim.x) s += partial[(size_t)i * 128 + c];
    sm[threadIdx.x] = s;
    __syncthreads();
    for (int off = 128; off >= 1; off >>= 1) {
        if (threadIdx.x < off) sm[threadIdx.x] += sm[threadIdx.x + off];
        __syncthreads();
    }
    if (threadIdx.x == 0) bnstat[c] = sm[0];
}

// ---- k3b: mu, rstd ----
__global__ void k3b(const float* __restrict__ bnsum, const float* __restrict__ bnsq,
                    float* __restrict__ mu, float* __restrict__ rstd, int N) {
    int d = threadIdx.x;
    float m = bnsum[d] / (float)N;
    float v = bnsq[d] / (float)N - m * m;
    mu[d] = m;
    rstd[d] = rsqrtf(v + 1e-5f);
}

// ---- k3c: BN + ELU -> xl2, xr2 (wave per node) ----
__global__ void k3c(const float* __restrict__ h, const float* __restrict__ mu,
                    const float* __restrict__ rstd, const float* __restrict__ gamma,
                    const float* __restrict__ beta,
                    const float* __restrict__ Wl, const float* __restrict__ bl,
                    const float* __restrict__ Wr, const float* __restrict__ br,
                    float* __restrict__ xl2, float* __restrict__ xr2, int N) {
    __shared__ float sh[4][64];
    int w = threadIdx.x >> 6, lane = threadIdx.x & 63;
    int n = blockIdx.x * 4 + w;
    bool valid = (n < N);
    if (valid) {
        float hv = h[(size_t)n * 64 + lane];
        hv = (hv - mu[lane]) * rstd[lane] * gamma[lane] + beta[lane];
        sh[w][lane] = elu1(hv);
    }
    __syncthreads();
    if (!valid) return;
    int c = lane & 31;
    const float* W = (lane < 32) ? Wl : Wr;
    const float* b = (lane < 32) ? bl : br;
    float acc = b[c];
    #pragma unroll
    for (int k = 0; k < 64; ++k) acc += sh[w][k] * W[k * 32 + c];
    ((lane < 32) ? xl2 : xr2)[(size_t)n * 32 + c] = acc;
}

// ---- kL2: 32 lanes per node: gather xl2[src] rows, single-pass softmax-sum
//      (no max-sub), write normalized h2 + denom + evbuf[orig]. No atomics. ----
__global__ void kL2(const float* __restrict__ xl2, const float* __restrict__ xr2,
                    const int4* __restrict__ edgeS,
                    const int* __restrict__ rowst, const int* __restrict__ cntA,
                    const float* __restrict__ We, const float* __restrict__ att,
                    float* __restrict__ evbuf, float* __restrict__ h2,
                    float* __restrict__ denom2, int N) {
    int g = blockIdx.x * blockDim.x + threadIdx.x;
    int n = g >> 5, c = g & 31;
    if (n >= N) return;
    float wev = We[c], attv = att[c];
    float xrv = xr2[(size_t)n * 32 + c];
    int start = rowst[n], len = cntA[n] + 1;
    float den = 0.f, acc = 0.f;
    for (int i = 0; i < len; ++i) {
        int4 e4 = edgeS[start + i];
        float eav = __int_as_float(e4.y);
        float xlv = xl2[(size_t)e4.x * 32 + c];
        float p = lrelu(xlv + xrv + eav * wev) * attv;
        float l = hredsum(p);
        float ev = expf(l);
        den += ev; acc += ev * xlv;
        if (c == 0) evbuf[e4.z] = ev;
    }
    float inv = 1.f / (den + 1e-16f);
    h2[(size_t)n * 32 + c] = acc * inv;
    if (c == 0) denom2[n] = den;
}

// ---- k4c: alpha output (original edge order, coalesced) ----
__global__ void k4c(const float* __restrict__ evbuf, const int* __restrict__ dstA,
                    const float* __restrict__ denom, float* __restrict__ alpha, int E, int Et) {
    int t = blockIdx.x * blockDim.x + threadIdx.x;
    if (t >= Et) return;
    int d = (t < E) ? dstA[t] : (t - E);
    alpha[t] = evbuf[t] / (denom[d] + 1e-16f);
}

// ---- k5: h2 -> +bias2 -> elu -> two streamed MLP heads -> log_softmax.
//      t1/c1 arrays eliminated (streamed into lt/lc accumulators);
//      launch_bounds(256,1) lets the allocator keep everything in VGPRs. ----
__global__ void __launch_bounds__(256, 1)
k5(const float* __restrict__ h2, const float* __restrict__ bias2,
   const float* __restrict__ Wt1, const float* __restrict__ bt1,
   const float* __restrict__ Wt2, const float* __restrict__ bt2,
   const float* __restrict__ Wc1, const float* __restrict__ bc1,
   const float* __restrict__ Wc2, const float* __restrict__ bc2,
   float* __restrict__ out, int N) {
    __shared__ float sWt1[1024], sWc1[1024], sWt2[640], sWc2[320];
    __shared__ float sbt1[32], sbc1[32], sbt2[20], sbc2[10], sb2[32];
    for (int i = threadIdx.x; i < 1024; i += blockDim.x) { sWt1[i] = Wt1[i]; sWc1[i] = Wc1[i]; }
    for (int i = threadIdx.x; i < 640; i += blockDim.x) sWt2[i] = Wt2[i];
    for (int i = threadIdx.x; i < 320; i += blockDim.x) sWc2[i] = Wc2[i];
    if (threadIdx.x < 32) { sbt1[threadIdx.x] = bt1[threadIdx.x]; sbc1[threadIdx.x] = bc1[threadIdx.x]; sb2[threadIdx.x] = bias2[threadIdx.x]; }
    if (threadIdx.x < 20) sbt2[threadIdx.x] = bt2[threadIdx.x];
    if (threadIdx.x < 10) sbc2[threadIdx.x] = bc2[threadIdx.x];
    __syncthreads();
    int n = blockIdx.x * blockDim.x + threadIdx.x;
    if (n >= N) return;
    float h[32];
    #pragma unroll
    for (int k = 0; k < 32; ++k) h[k] = elu1(h2[(size_t)n * 32 + k] + sb2[k]);
    float lt[20], lc[10];
    #pragma unroll
    for (int o = 0; o < 20; ++o) lt[o] = sbt2[o];
    #pragma unroll
    for (int o = 0; o < 10; ++o) lc[o] = sbc2[o];
    #pragma unroll
    for (int j = 0; j < 32; ++j) {
        float at = sbt1[j], ac = sbc1[j];
        #pragma unroll
        for (int k = 0; k < 32; ++k) { at += h[k] * sWt1[k * 32 + j]; ac += h[k] * sWc1[k * 32 + j]; }
        float tj = fmaxf(at, 0.f), cj = fmaxf(ac, 0.f);
        #pragma unroll
        for (int o = 0; o < 20; ++o) lt[o] += tj * sWt2[j * 20 + o];
        #pragma unroll
        for (int o = 0; o < 10; ++o) lc[o] += cj * sWc2[j * 10 + o];
    }
    float mt = -1e30f, mc = -1e30f;
    #pragma unroll
    for (int o = 0; o < 20; ++o) mt = fmaxf(mt, lt[o]);
    #pragma unroll
    for (int o = 0; o < 10; ++o) mc = fmaxf(mc, lc[o]);
    float st = 0.f, sc = 0.f;
    #pragma unroll
    for (int o = 0; o < 20; ++o) st += expf(lt[o] - mt);
    #pragma unroll
    for (int o = 0; o < 10; ++o) sc += expf(lc[o] - mc);
    float lset = mt + logf(st);
    float lsec = mc + logf(sc);
    #pragma unroll
    for (int o = 0; o < 10; ++o) out[(size_t)n * 30 + o] = lc[o] - lsec;
    #pragma unroll
    for (int o = 0; o < 20; ++o) out[(size_t)n * 30 + 10 + o] = lt[o] - lset;
}

extern "C" void kernel_launch(void* const* d_in, const int* in_sizes, int n_in,
                              void* d_out, int out_size, void* d_ws, size_t ws_size,
                              hipStream_t stream) {
    const float* x     = (const float*)d_in[0];
    const int*   ei    = (const int*)d_in[1];
    const float* eattr = (const float*)d_in[2];
    const float* Wl1   = (const float*)d_in[3];
    const float* bl1   = (const float*)d_in[4];
    const float* Wr1   = (const float*)d_in[5];
    const float* br1   = (const float*)d_in[6];
    const float* We1   = (const float*)d_in[7];
    const float* att1  = (const float*)d_in[8];
    const float* bias1 = (const float*)d_in[9];
    const float* skW   = (const float*)d_in[10];
    const float* skb   = (const float*)d_in[11];
    const float* gamma = (const float*)d_in[12];
    const float* beta  = (const float*)d_in[13];
    const float* Wl2   = (const float*)d_in[14];
    const float* bl2   = (const float*)d_in[15];
    const float* Wr2   = (const float*)d_in[16];
    const float* br2   = (const float*)d_in[17];
    const float* We2   = (const float*)d_in[18];
    const float* att2  = (const float*)d_in[19];
    const float* bias2 = (const float*)d_in[20];
    const float* Wc1   = (const float*)d_in[21];
    const float* bc1   = (const float*)d_in[22];
    const float* Wc2   = (const float*)d_in[23];
    const float* bc2   = (const float*)d_in[24];
    const float* Wt1   = (const float*)d_in[25];
    const float* bt1   = (const float*)d_in[26];
    const float* Wt2   = (const float*)d_in[27];
    const float* bt2   = (const float*)d_in[28];

    const int N  = in_sizes[0] / 2;
    const int E  = in_sizes[1] / 2;
    const int Et = E + N;
    const int* srcA = ei;
    const int* dstA = ei + E;
    const int G3 = 1024;
    const int B  = (N + 255) / 256;

    // workspace carve
    char* p = (char*)d_ws;
    unsigned long long* packed = (unsigned long long*)p; p += (size_t)N * 8;
    int*   cursor = (int*)p;   p += (size_t)N * 4;
    int4*  edgeS  = (int4*)p;  p += (size_t)Et * 16;
    float* hbuf   = (float*)p; p += (size_t)N * 64 * 4;   // h rows; reused as h2 (N*32)
    float* xl2    = (float*)p; p += (size_t)N * 32 * 4;
    float* xr2    = (float*)p; p += (size_t)N * 32 * 4;
    float* evbuf  = (float*)p; p += (size_t)Et * 4;
    float* dstat  = (float*)p; p += (size_t)N * 6 * 4;
    int*   cntA   = (int*)p;   p += (size_t)N * 4;
    float* asumA  = (float*)p; p += (size_t)N * 4;
    int*   rowst  = (int*)p;   p += (size_t)N * 4;
    int*   bsum   = (int*)p;   p += 512 * 4;
    float* partial= (float*)p; p += (size_t)G3 * 128 * 4;
    float* bnstat = (float*)p; p += 128 * 4;
    float* mu     = (float*)p; p += 64 * 4;
    float* rstd   = (float*)p; p += 64 * 4;
    float* denom2 = (float*)p; p += (size_t)N * 4;
    float* h2     = hbuf;

    float* outMain  = (float*)d_out;
    float* outAlpha = outMain + (size_t)N * 30;

    // ---- CSR build (atomic-light) ----
    hipMemsetAsync(packed, 0, (size_t)N * 12, stream);    // packed + cursor
    k0p<<<(E + 255) / 256, 256, 0, stream>>>(dstA, eattr, packed, E);
    kscanA<<<B, 256, 0, stream>>>(packed, rowst, bsum, cntA, asumA, N);
    kscanB<<<1, 512, 0, stream>>>(bsum, B);
    kscanC<<<B, 256, 0, stream>>>(rowst, bsum, N);
    kscatter<<<(Et + 255) / 256, 256, 0, stream>>>(srcA, dstA, eattr, asumA, cntA,
                                                   rowst, cursor, edgeS, E, Et);

    // ---- layer 1 (gather, zero atomics) ----
    kL1<<<((size_t)2 * N + 255) / 256, 256, 0, stream>>>(x, edgeS, rowst, cntA,
                                                         Wl1, bl1, Wr1, br1, We1, att1,
                                                         dstat, N);

    // ---- node reconstruction + skip + BN ----
    k3a<<<G3, 256, 0, stream>>>(x, dstat, Wl1, bl1, bias1, skW, skb, hbuf, partial, N);
    kred<<<128, 256, 0, stream>>>(partial, bnstat, G3);
    k3b<<<1, 64, 0, stream>>>(bnstat, bnstat + 64, mu, rstd, N);
    k3c<<<(N + 3) / 4, 256, 0, stream>>>(hbuf, mu, rstd, gamma, beta,
                                         Wl2, bl2, Wr2, br2, xl2, xr2, N);

    // ---- layer 2 (gather, zero atomics) ----
    kL2<<<((size_t)N * 32 + 255) / 256, 256, 0, stream>>>(xl2, xr2, edgeS, rowst, cntA,
                                                          We2, att2, evbuf, h2, denom2, N);
    k4c<<<(Et + 255) / 256, 256, 0, stream>>>(evbuf, dstA, denom2, outAlpha, E, Et);

    // ---- heads ----
    k5<<<(N + 255) / 256, 256, 0, stream>>>(h2, bias2, Wt1, bt1, Wt2, bt2,
                                            Wc1, bc1, Wc2, bc2, outMain, N);
    (void)n_in; (void)out_size; (void)ws_size;
}

// Round 7
// 549.978 us; speedup vs baseline: 7.2024x; 1.3575x over previous
//
#include <hip/hip_runtime.h>
#include <math.h>

#define NEG_SLOPE 0.2f
#define CNT_SHIFT 44
#define EA_SCALE 262144.0f          // 2^18 fixed-point for edge_attr sums
#define EA_INV (1.0f / 262144.0f)
#define L1TILE 3072                 // int4 entries staged in LDS (48 KB)

__device__ __forceinline__ float lrelu(float x) { return x > 0.f ? x : NEG_SLOPE * x; }
__device__ __forceinline__ float elu1(float x) { return x > 0.f ? x : expf(x) - 1.f; }

__device__ __forceinline__ float hredsum(float v) {  // reduce within 32-lane half
    #pragma unroll
    for (int m = 16; m; m >>= 1) v += __shfl_xor(v, m);
    return v;
}

// ---- k0p: one u64 atomic per edge: packed[d] += (1<<44) | fix18(ea) ----
__global__ void k0p(const int* __restrict__ dst, const float* __restrict__ ea,
                    unsigned long long* __restrict__ packed, int E) {
    int t = blockIdx.x * blockDim.x + threadIdx.x;
    if (t >= E) return;
    int d = dst[t];
    unsigned long long inc = (1ULL << CNT_SHIFT)
                           | (unsigned long long)__float2uint_rn(ea[t] * EA_SCALE);
    atomicAdd(&packed[d], inc);
}

// ---- kscanA: per-block inclusive scan of (cnt[i]+1); unpack cnt/asum ----
__global__ void kscanA(const unsigned long long* __restrict__ packed,
                       int* __restrict__ rowstart, int* __restrict__ bsum,
                       int* __restrict__ cntA, float* __restrict__ asumA, int N) {
    __shared__ int sm[256];
    int t = threadIdx.x;
    int i = blockIdx.x * 256 + t;
    int v = 0;
    if (i < N) {
        unsigned long long p = packed[i];
        int c = (int)(p >> CNT_SHIFT);
        cntA[i] = c;
        asumA[i] = (float)(p & ((1ULL << CNT_SHIFT) - 1)) * EA_INV;
        v = c + 1;
    }
    sm[t] = v;
    __syncthreads();
    for (int off = 1; off < 256; off <<= 1) {
        int u = (t >= off) ? sm[t - off] : 0;
        __syncthreads();
        sm[t] += u;
        __syncthreads();
    }
    if (i < N) rowstart[i] = sm[t] - v;
    if (t == 255) bsum[blockIdx.x] = sm[255];
}

__global__ void kscanB(int* __restrict__ bsum, int B) {
    __shared__ int sm[512];
    int t = threadIdx.x;
    int v = (t < B) ? bsum[t] : 0;
    sm[t] = v;
    __syncthreads();
    for (int off = 1; off < 512; off <<= 1) {
        int u = (t >= off) ? sm[t - off] : 0;
        __syncthreads();
        sm[t] += u;
        __syncthreads();
    }
    if (t < B) bsum[t] = sm[t] - v;  // exclusive block offsets
}

__global__ void kscanC(int* __restrict__ rowstart, const int* __restrict__ bsum, int N) {
    int i = blockIdx.x * blockDim.x + threadIdx.x;
    if (i < N) rowstart[i] += bsum[i >> 8];
}

// ---- kscatter: edgeS[pos] = {src, ea_bits, orig, 0}; self-loop slot = cnt[d], no atomic ----
__global__ void kscatter(const int* __restrict__ srcA, const int* __restrict__ dstA,
                         const float* __restrict__ ea, const float* __restrict__ asumA,
                         const int* __restrict__ cntA, const int* __restrict__ rowstart,
                         int* __restrict__ cursor, int4* __restrict__ edgeS, int E, int Et) {
    int t = blockIdx.x * blockDim.x + threadIdx.x;
    if (t >= Et) return;
    if (t < E) {
        int d = dstA[t];
        int c = atomicAdd(&cursor[d], 1);
        int cd = cntA[d];
        int pos = rowstart[d] + min(c, cd - 1);   // clamp keeps replays in-range
        edgeS[pos] = make_int4(srcA[t], __float_as_int(ea[t]), t, 0);
    } else {
        int d = t - E;
        int cd = cntA[d];
        int pos = rowstart[d] + cd;
        float eav = asumA[d] / fmaxf((float)cd, 1.0f);
        edgeS[pos] = make_int4(d, __float_as_int(eav), t, 0);
    }
}

// ---- kL1: LDS-tiled CSR consumption. Block = 128 consecutive nodes x 2 heads.
//      The block's contiguous edge range streams through LDS with coalesced
//      16B/lane loads; threads consume their node's entries from LDS.
//      Zero atomics, no cacheline amplification. ----
__global__ void __launch_bounds__(256, 2)
kL1(const float* __restrict__ x, const int4* __restrict__ edgeS,
    const int* __restrict__ rowst, const int* __restrict__ cntA,
    const float* __restrict__ Wl, const float* __restrict__ bl,
    const float* __restrict__ Wr, const float* __restrict__ br,
    const float* __restrict__ We, const float* __restrict__ att,
    float* __restrict__ dstat, int N, int Et) {
    __shared__ float sW[7][64];  // wl0, wl1, we, att, wr0, wr1, (bl+br)
    __shared__ int4 sTile[L1TILE];
    if (threadIdx.x < 64) {
        int d = threadIdx.x;
        sW[0][d] = Wl[d];  sW[1][d] = Wl[64 + d];
        sW[2][d] = We[d];  sW[3][d] = att[d];
        sW[4][d] = Wr[d];  sW[5][d] = Wr[64 + d];
        sW[6][d] = bl[d] + br[d];
    }

    int n0 = blockIdx.x * 128;
    int nEnd = min(n0 + 128, N);
    int n = n0 + (threadIdx.x >> 1), h = threadIdx.x & 1;
    bool valid = (n < N);
    int base = h * 32;

    int eStart = rowst[n0];
    int eEnd = (nEnd < N) ? rowst[nEnd] : Et;
    int myStart = 0, myEnd = 0;
    float2 xd = make_float2(0.f, 0.f);
    if (valid) {
        myStart = rowst[n];
        myEnd = myStart + cntA[n] + 1;
        xd = ((const float2*)x)[n];
    }
    __syncthreads();   // sW ready

    float dstp[32];
    #pragma unroll
    for (int c = 0; c < 32; ++c) {
        int dc = base + c;
        dstp[c] = xd.x * sW[4][dc] + xd.y * sW[5][dc] + sW[6][dc];
    }

    float pd = 0.f, pa = 0.f, pb = 0.f;
    for (int tb = eStart; tb < eEnd; tb += L1TILE) {
        int tileLen = min(L1TILE, eEnd - tb);
        __syncthreads();   // previous tile fully consumed
        for (int j = threadIdx.x; j < tileLen; j += 256) sTile[j] = edgeS[tb + j];
        __syncthreads();
        int lo = max(myStart, tb), hi = min(myEnd, tb + tileLen);
        for (int e = lo; e < hi; ++e) {
            int4 e4 = sTile[e - tb];
            float2 xs = ((const float2*)x)[e4.x];
            float eav = __int_as_float(e4.y);
            float l = 0.f;
            #pragma unroll
            for (int c = 0; c < 32; ++c) {
                int dc = base + c;
                float m = dstp[c] + xs.x * sW[0][dc] + xs.y * sW[1][dc] + eav * sW[2][dc];
                l += lrelu(m) * sW[3][dc];
            }
            float ev = expf(l);
            pd += ev; pa += ev * xs.x; pb += ev * xs.y;
        }
    }
    if (valid) {
        dstat[(size_t)n * 6 + h]     = pd;
        dstat[(size_t)n * 6 + 2 + h] = pa;
        dstat[(size_t)n * 6 + 4 + h] = pb;
    }
}

// ---- k3a: reconstruct h = agg/denom + bias1 + skip; BN partials ----
__global__ void k3a(const float* __restrict__ x, const float* __restrict__ dstat,
                    const float* __restrict__ Wl, const float* __restrict__ bl,
                    const float* __restrict__ bias1,
                    const float* __restrict__ skW, const float* __restrict__ skb,
                    float* __restrict__ hout, float* __restrict__ partial, int N) {
    __shared__ float sv[256], sq[256];
    size_t total = (size_t)N * 64;
    size_t stride = (size_t)gridDim.x * blockDim.x;
    float s = 0.f, q = 0.f;
    for (size_t idx = (size_t)blockIdx.x * blockDim.x + threadIdx.x; idx < total; idx += stride) {
        int n = (int)(idx >> 6), d = (int)(idx & 63), h2 = d >> 5;
        const float* ps = &dstat[(size_t)n * 6];
        float den = ps[h2], t0 = ps[2 + h2], t1 = ps[4 + h2];
        float agg = t0 * Wl[d] + t1 * Wl[64 + d] + den * bl[d];
        float hv = agg / (den + 1e-16f) + bias1[d]
                 + x[2 * n] * skW[d] + x[2 * n + 1] * skW[64 + d] + skb[d];
        hout[idx] = hv;
        s += hv; q += hv * hv;
    }
    sv[threadIdx.x] = s; sq[threadIdx.x] = q;
    __syncthreads();
    if (threadIdx.x < 64) {
        float a = sv[threadIdx.x] + sv[threadIdx.x + 64] + sv[threadIdx.x + 128] + sv[threadIdx.x + 192];
        float b = sq[threadIdx.x] + sq[threadIdx.x + 64] + sq[threadIdx.x + 128] + sq[threadIdx.x + 192];
        partial[(size_t)blockIdx.x * 128 + threadIdx.x] = a;
        partial[(size_t)blockIdx.x * 128 + 64 + threadIdx.x] = b;
    }
}

// ---- Kred: reduce per-block BN partials ----
__global__ void kred(const float* __restrict__ partial, float* __restrict__ bnstat, int G) {
    __shared__ float sm[256];
    int c = blockIdx.x;
    float s = 0.f;
    for (int i = threadIdx.x; i < G; i += blockDim.x) s += partial[(size_t)i * 128 + c];
    sm[threadIdx.x] = s;
    __syncthreads();
    for (int off = 128; off >= 1; off >>= 1) {
        if (threadIdx.x < off) sm[threadIdx.x] += sm[threadIdx.x + off];
        __syncthreads();
    }
    if (threadIdx.x == 0) bnstat[c] = sm[0];
}

// ---- k3b: mu, rstd ----
__global__ void k3b(const float* __restrict__ bnsum, const float* __restrict__ bnsq,
                    float* __restrict__ mu, float* __restrict__ rstd, int N) {
    int d = threadIdx.x;
    float m = bnsum[d] / (float)N;
    float v = bnsq[d] / (float)N - m * m;
    mu[d] = m;
    rstd[d] = rsqrtf(v + 1e-5f);
}

// ---- k3c: BN + ELU -> xl2, xr2 (wave per node) ----
__global__ void k3c(const float* __restrict__ h, const float* __restrict__ mu,
                    const float* __restrict__ rstd, const float* __restrict__ gamma,
                    const float* __restrict__ beta,
                    const float* __restrict__ Wl, const float* __restrict__ bl,
                    const float* __restrict__ Wr, const float* __restrict__ br,
                    float* __restrict__ xl2, float* __restrict__ xr2, int N) {
    __shared__ float sh[4][64];
    int w = threadIdx.x >> 6, lane = threadIdx.x & 63;
    int n = blockIdx.x * 4 + w;
    bool valid = (n < N);
    if (valid) {
        float hv = h[(size_t)n * 64 + lane];
        hv = (hv - mu[lane]) * rstd[lane] * gamma[lane] + beta[lane];
        sh[w][lane] = elu1(hv);
    }
    __syncthreads();
    if (!valid) return;
    int c = lane & 31;
    const float* W = (lane < 32) ? Wl : Wr;
    const float* b = (lane < 32) ? bl : br;
    float acc = b[c];
    #pragma unroll
    for (int k = 0; k < 64; ++k) acc += sh[w][k] * W[k * 32 + c];
    ((lane < 32) ? xl2 : xr2)[(size_t)n * 32 + c] = acc;
}

// ---- kL2: 32 lanes per node: gather xl2[src] rows, single-pass softmax-sum
//      (no max-sub), write normalized h2 + denom + evbuf[orig]. No atomics. ----
__global__ void kL2(const float* __restrict__ xl2, const float* __restrict__ xr2,
                    const int4* __restrict__ edgeS,
                    const int* __restrict__ rowst, const int* __restrict__ cntA,
                    const float* __restrict__ We, const float* __restrict__ att,
                    float* __restrict__ evbuf, float* __restrict__ h2,
                    float* __restrict__ denom2, int N) {
    int g = blockIdx.x * blockDim.x + threadIdx.x;
    int n = g >> 5, c = g & 31;
    if (n >= N) return;
    float wev = We[c], attv = att[c];
    float xrv = xr2[(size_t)n * 32 + c];
    int start = rowst[n], len = cntA[n] + 1;
    float den = 0.f, acc = 0.f;
    for (int i = 0; i < len; ++i) {
        int4 e4 = edgeS[start + i];
        float eav = __int_as_float(e4.y);
        float xlv = xl2[(size_t)e4.x * 32 + c];
        float p = lrelu(xlv + xrv + eav * wev) * attv;
        float l = hredsum(p);
        float ev = expf(l);
        den += ev; acc += ev * xlv;
        if (c == 0) evbuf[e4.z] = ev;
    }
    float inv = 1.f / (den + 1e-16f);
    h2[(size_t)n * 32 + c] = acc * inv;
    if (c == 0) denom2[n] = den;
}

// ---- k4c: alpha output (original edge order, coalesced) ----
__global__ void k4c(const float* __restrict__ evbuf, const int* __restrict__ dstA,
                    const float* __restrict__ denom, float* __restrict__ alpha, int E, int Et) {
    int t = blockIdx.x * blockDim.x + threadIdx.x;
    if (t >= Et) return;
    int d = (t < E) ? dstA[t] : (t - E);
    alpha[t] = evbuf[t] / (denom[d] + 1e-16f);
}

// ---- k5: h2 -> +bias2 -> elu -> two streamed MLP heads -> log_softmax ----
__global__ void __launch_bounds__(256, 1)
k5(const float* __restrict__ h2, const float* __restrict__ bias2,
   const float* __restrict__ Wt1, const float* __restrict__ bt1,
   const float* __restrict__ Wt2, const float* __restrict__ bt2,
   const float* __restrict__ Wc1, const float* __restrict__ bc1,
   const float* __restrict__ Wc2, const float* __restrict__ bc2,
   float* __restrict__ out, int N) {
    __shared__ float sWt1[1024], sWc1[1024], sWt2[640], sWc2[320];
    __shared__ float sbt1[32], sbc1[32], sbt2[20], sbc2[10], sb2[32];
    for (int i = threadIdx.x; i < 1024; i += blockDim.x) { sWt1[i] = Wt1[i]; sWc1[i] = Wc1[i]; }
    for (int i = threadIdx.x; i < 640; i += blockDim.x) sWt2[i] = Wt2[i];
    for (int i = threadIdx.x; i < 320; i += blockDim.x) sWc2[i] = Wc2[i];
    if (threadIdx.x < 32) { sbt1[threadIdx.x] = bt1[threadIdx.x]; sbc1[threadIdx.x] = bc1[threadIdx.x]; sb2[threadIdx.x] = bias2[threadIdx.x]; }
    if (threadIdx.x < 20) sbt2[threadIdx.x] = bt2[threadIdx.x];
    if (threadIdx.x < 10) sbc2[threadIdx.x] = bc2[threadIdx.x];
    __syncthreads();
    int n = blockIdx.x * blockDim.x + threadIdx.x;
    if (n >= N) return;
    float h[32];
    #pragma unroll
    for (int k = 0; k < 32; ++k) h[k] = elu1(h2[(size_t)n * 32 + k] + sb2[k]);
    float lt[20], lc[10];
    #pragma unroll
    for (int o = 0; o < 20; ++o) lt[o] = sbt2[o];
    #pragma unroll
    for (int o = 0; o < 10; ++o) lc[o] = sbc2[o];
    #pragma unroll
    for (int j = 0; j < 32; ++j) {
        float at = sbt1[j], ac = sbc1[j];
        #pragma unroll
        for (int k = 0; k < 32; ++k) { at += h[k] * sWt1[k * 32 + j]; ac += h[k] * sWc1[k * 32 + j]; }
        float tj = fmaxf(at, 0.f), cj = fmaxf(ac, 0.f);
        #pragma unroll
        for (int o = 0; o < 20; ++o) lt[o] += tj * sWt2[j * 20 + o];
        #pragma unroll
        for (int o = 0; o < 10; ++o) lc[o] += cj * sWc2[j * 10 + o];
    }
    float mt = -1e30f, mc = -1e30f;
    #pragma unroll
    for (int o = 0; o < 20; ++o) mt = fmaxf(mt, lt[o]);
    #pragma unroll
    for (int o = 0; o < 10; ++o) mc = fmaxf(mc, lc[o]);
    float st = 0.f, sc = 0.f;
    #pragma unroll
    for (int o = 0; o < 20; ++o) st += expf(lt[o] - mt);
    #pragma unroll
    for (int o = 0; o < 10; ++o) sc += expf(lc[o] - mc);
    float lset = mt + logf(st);
    float lsec = mc + logf(sc);
    #pragma unroll
    for (int o = 0; o < 10; ++o) out[(size_t)n * 30 + o] = lc[o] - lsec;
    #pragma unroll
    for (int o = 0; o < 20; ++o) out[(size_t)n * 30 + 10 + o] = lt[o] - lset;
}

extern "C" void kernel_launch(void* const* d_in, const int* in_sizes, int n_in,
                              void* d_out, int out_size, void* d_ws, size_t ws_size,
                              hipStream_t stream) {
    const float* x     = (const float*)d_in[0];
    const int*   ei    = (const int*)d_in[1];
    const float* eattr = (const float*)d_in[2];
    const float* Wl1   = (const float*)d_in[3];
    const float* bl1   = (const float*)d_in[4];
    const float* Wr1   = (const float*)d_in[5];
    const float* br1   = (const float*)d_in[6];
    const float* We1   = (const float*)d_in[7];
    const float* att1  = (const float*)d_in[8];
    const float* bias1 = (const float*)d_in[9];
    const float* skW   = (const float*)d_in[10];
    const float* skb   = (const float*)d_in[11];
    const float* gamma = (const float*)d_in[12];
    const float* beta  = (const float*)d_in[13];
    const float* Wl2   = (const float*)d_in[14];
    const float* bl2   = (const float*)d_in[15];
    const float* Wr2   = (const float*)d_in[16];
    const float* br2   = (const float*)d_in[17];
    const float* We2   = (const float*)d_in[18];
    const float* att2  = (const float*)d_in[19];
    const float* bias2 = (const float*)d_in[20];
    const float* Wc1   = (const float*)d_in[21];
    const float* bc1   = (const float*)d_in[22];
    const float* Wc2   = (const float*)d_in[23];
    const float* bc2   = (const float*)d_in[24];
    const float* Wt1   = (const float*)d_in[25];
    const float* bt1   = (const float*)d_in[26];
    const float* Wt2   = (const float*)d_in[27];
    const float* bt2   = (const float*)d_in[28];

    const int N  = in_sizes[0] / 2;
    const int E  = in_sizes[1] / 2;
    const int Et = E + N;
    const int* srcA = ei;
    const int* dstA = ei + E;
    const int G3 = 1024;
    const int B  = (N + 255) / 256;

    // workspace carve
    char* p = (char*)d_ws;
    unsigned long long* packed = (unsigned long long*)p; p += (size_t)N * 8;
    int*   cursor = (int*)p;   p += (size_t)N * 4;
    int4*  edgeS  = (int4*)p;  p += (size_t)Et * 16;
    float* hbuf   = (float*)p; p += (size_t)N * 64 * 4;   // h rows; reused as h2 (N*32)
    float* xl2    = (float*)p; p += (size_t)N * 32 * 4;
    float* xr2    = (float*)p; p += (size_t)N * 32 * 4;
    float* evbuf  = (float*)p; p += (size_t)Et * 4;
    float* dstat  = (float*)p; p += (size_t)N * 6 * 4;
    int*   cntA   = (int*)p;   p += (size_t)N * 4;
    float* asumA  = (float*)p; p += (size_t)N * 4;
    int*   rowst  = (int*)p;   p += (size_t)N * 4;
    int*   bsum   = (int*)p;   p += 512 * 4;
    float* partial= (float*)p; p += (size_t)G3 * 128 * 4;
    float* bnstat = (float*)p; p += 128 * 4;
    float* mu     = (float*)p; p += 64 * 4;
    float* rstd   = (float*)p; p += 64 * 4;
    float* denom2 = (float*)p; p += (size_t)N * 4;
    float* h2     = hbuf;

    float* outMain  = (float*)d_out;
    float* outAlpha = outMain + (size_t)N * 30;

    // ---- CSR build (atomic-light) ----
    hipMemsetAsync(packed, 0, (size_t)N * 12, stream);    // packed + cursor
    k0p<<<(E + 255) / 256, 256, 0, stream>>>(dstA, eattr, packed, E);
    kscanA<<<B, 256, 0, stream>>>(packed, rowst, bsum, cntA, asumA, N);
    kscanB<<<1, 512, 0, stream>>>(bsum, B);
    kscanC<<<B, 256, 0, stream>>>(rowst, bsum, N);
    kscatter<<<(Et + 255) / 256, 256, 0, stream>>>(srcA, dstA, eattr, asumA, cntA,
                                                   rowst, cursor, edgeS, E, Et);

    // ---- layer 1 (LDS-tiled gather, zero atomics) ----
    kL1<<<(N + 127) / 128, 256, 0, stream>>>(x, edgeS, rowst, cntA,
                                             Wl1, bl1, Wr1, br1, We1, att1,
                                             dstat, N, Et);

    // ---- node reconstruction + skip + BN ----
    k3a<<<G3, 256, 0, stream>>>(x, dstat, Wl1, bl1, bias1, skW, skb, hbuf, partial, N);
    kred<<<128, 256, 0, stream>>>(partial, bnstat, G3);
    k3b<<<1, 64, 0, stream>>>(bnstat, bnstat + 64, mu, rstd, N);
    k3c<<<(N + 3) / 4, 256, 0, stream>>>(hbuf, mu, rstd, gamma, beta,
                                         Wl2, bl2, Wr2, br2, xl2, xr2, N);

    // ---- layer 2 (gather, zero atomics) ----
    kL2<<<((size_t)N * 32 + 255) / 256, 256, 0, stream>>>(xl2, xr2, edgeS, rowst, cntA,
                                                          We2, att2, evbuf, h2, denom2, N);
    k4c<<<(Et + 255) / 256, 256, 0, stream>>>(evbuf, dstA, denom2, outAlpha, E, Et);

    // ---- heads ----
    k5<<<(N + 255) / 256, 256, 0, stream>>>(h2, bias2, Wt1, bt1, Wt2, bt2,
                                            Wc1, bc1, Wc2, bc2, outMain, N);
    (void)n_in; (void)out_size; (void)ws_size;
}

// Round 8
// 444.996 us; speedup vs baseline: 8.9016x; 1.2359x over previous
//
#include <hip/hip_runtime.h>
#include <math.h>

#define NEG_SLOPE 0.2f
#define CNT_SHIFT 44
#define EA_SCALE 262144.0f          // 2^18 fixed-point for edge_attr sums
#define EA_INV (1.0f / 262144.0f)
#define L1TILE 3072                 // int4 entries staged in LDS (48 KB)

__device__ __forceinline__ float lrelu(float x) { return x > 0.f ? x : NEG_SLOPE * x; }
__device__ __forceinline__ float elu1(float x) { return x > 0.f ? x : expf(x) - 1.f; }

__device__ __forceinline__ float hredsum(float v) {  // reduce within 32-lane half
    #pragma unroll
    for (int m = 16; m; m >>= 1) v += __shfl_xor(v, m);
    return v;
}

// ---- k0p: one u64 atomic per edge: packed[d] += (1<<44) | fix18(ea) ----
__global__ void k0p(const int* __restrict__ dst, const float* __restrict__ ea,
                    unsigned long long* __restrict__ packed, int E) {
    int t = blockIdx.x * blockDim.x + threadIdx.x;
    if (t >= E) return;
    int d = dst[t];
    unsigned long long inc = (1ULL << CNT_SHIFT)
                           | (unsigned long long)__float2uint_rn(ea[t] * EA_SCALE);
    atomicAdd(&packed[d], inc);
}

// ---- kscanA: per-block inclusive scan of (cnt[i]+1); unpack cnt/asum ----
__global__ void kscanA(const unsigned long long* __restrict__ packed,
                       int* __restrict__ rowstart, int* __restrict__ bsum,
                       int* __restrict__ cntA, float* __restrict__ asumA, int N) {
    __shared__ int sm[256];
    int t = threadIdx.x;
    int i = blockIdx.x * 256 + t;
    int v = 0;
    if (i < N) {
        unsigned long long p = packed[i];
        int c = (int)(p >> CNT_SHIFT);
        cntA[i] = c;
        asumA[i] = (float)(p & ((1ULL << CNT_SHIFT) - 1)) * EA_INV;
        v = c + 1;
    }
    sm[t] = v;
    __syncthreads();
    for (int off = 1; off < 256; off <<= 1) {
        int u = (t >= off) ? sm[t - off] : 0;
        __syncthreads();
        sm[t] += u;
        __syncthreads();
    }
    if (i < N) rowstart[i] = sm[t] - v;
    if (t == 255) bsum[blockIdx.x] = sm[255];
}

__global__ void kscanB(int* __restrict__ bsum, int B) {
    __shared__ int sm[512];
    int t = threadIdx.x;
    int v = (t < B) ? bsum[t] : 0;
    sm[t] = v;
    __syncthreads();
    for (int off = 1; off < 512; off <<= 1) {
        int u = (t >= off) ? sm[t - off] : 0;
        __syncthreads();
        sm[t] += u;
        __syncthreads();
    }
    if (t < B) bsum[t] = sm[t] - v;  // exclusive block offsets
}

__global__ void kscanC(int* __restrict__ rowstart, const int* __restrict__ bsum, int N) {
    int i = blockIdx.x * blockDim.x + threadIdx.x;
    if (i < N) rowstart[i] += bsum[i >> 8];
}

// ---- kscatter: edgeS[pos] = {src, ea_bits, orig, 0}; self-loop slot = cnt[d], no atomic ----
__global__ void kscatter(const int* __restrict__ srcA, const int* __restrict__ dstA,
                         const float* __restrict__ ea, const float* __restrict__ asumA,
                         const int* __restrict__ cntA, const int* __restrict__ rowstart,
                         int* __restrict__ cursor, int4* __restrict__ edgeS, int E, int Et) {
    int t = blockIdx.x * blockDim.x + threadIdx.x;
    if (t >= Et) return;
    if (t < E) {
        int d = dstA[t];
        int c = atomicAdd(&cursor[d], 1);
        int cd = cntA[d];
        int pos = rowstart[d] + min(c, cd - 1);   // clamp keeps replays in-range
        edgeS[pos] = make_int4(srcA[t], __float_as_int(ea[t]), t, 0);
    } else {
        int d = t - E;
        int cd = cntA[d];
        int pos = rowstart[d] + cd;
        float eav = asumA[d] / fmaxf((float)cd, 1.0f);
        edgeS[pos] = make_int4(d, __float_as_int(eav), t, 0);
    }
}

// ---- kL1: LDS-tiled CSR consumption. Block = 128 consecutive nodes x 2 heads. ----
__global__ void __launch_bounds__(256, 2)
kL1(const float* __restrict__ x, const int4* __restrict__ edgeS,
    const int* __restrict__ rowst, const int* __restrict__ cntA,
    const float* __restrict__ Wl, const float* __restrict__ bl,
    const float* __restrict__ Wr, const float* __restrict__ br,
    const float* __restrict__ We, const float* __restrict__ att,
    float* __restrict__ dstat, int N, int Et) {
    __shared__ float sW[7][64];  // wl0, wl1, we, att, wr0, wr1, (bl+br)
    __shared__ int4 sTile[L1TILE];
    if (threadIdx.x < 64) {
        int d = threadIdx.x;
        sW[0][d] = Wl[d];  sW[1][d] = Wl[64 + d];
        sW[2][d] = We[d];  sW[3][d] = att[d];
        sW[4][d] = Wr[d];  sW[5][d] = Wr[64 + d];
        sW[6][d] = bl[d] + br[d];
    }

    int n0 = blockIdx.x * 128;
    int nEnd = min(n0 + 128, N);
    int n = n0 + (threadIdx.x >> 1), h = threadIdx.x & 1;
    bool valid = (n < N);
    int base = h * 32;

    int eStart = rowst[n0];
    int eEnd = (nEnd < N) ? rowst[nEnd] : Et;
    int myStart = 0, myEnd = 0;
    float2 xd = make_float2(0.f, 0.f);
    if (valid) {
        myStart = rowst[n];
        myEnd = myStart + cntA[n] + 1;
        xd = ((const float2*)x)[n];
    }
    __syncthreads();   // sW ready

    float dstp[32];
    #pragma unroll
    for (int c = 0; c < 32; ++c) {
        int dc = base + c;
        dstp[c] = xd.x * sW[4][dc] + xd.y * sW[5][dc] + sW[6][dc];
    }

    float pd = 0.f, pa = 0.f, pb = 0.f;
    for (int tb = eStart; tb < eEnd; tb += L1TILE) {
        int tileLen = min(L1TILE, eEnd - tb);
        __syncthreads();   // previous tile fully consumed
        for (int j = threadIdx.x; j < tileLen; j += 256) sTile[j] = edgeS[tb + j];
        __syncthreads();
        int lo = max(myStart, tb), hi = min(myEnd, tb + tileLen);
        for (int e = lo; e < hi; ++e) {
            int4 e4 = sTile[e - tb];
            float2 xs = ((const float2*)x)[e4.x];
            float eav = __int_as_float(e4.y);
            float l = 0.f;
            #pragma unroll
            for (int c = 0; c < 32; ++c) {
                int dc = base + c;
                float m = dstp[c] + xs.x * sW[0][dc] + xs.y * sW[1][dc] + eav * sW[2][dc];
                l += lrelu(m) * sW[3][dc];
            }
            float ev = expf(l);
            pd += ev; pa += ev * xs.x; pb += ev * xs.y;
        }
    }
    if (valid) {
        dstat[(size_t)n * 6 + h]     = pd;
        dstat[(size_t)n * 6 + 2 + h] = pa;
        dstat[(size_t)n * 6 + 4 + h] = pb;
    }
}

// ---- k3a: reconstruct h = agg/denom + bias1 + skip; BN partials ----
__global__ void k3a(const float* __restrict__ x, const float* __restrict__ dstat,
                    const float* __restrict__ Wl, const float* __restrict__ bl,
                    const float* __restrict__ bias1,
                    const float* __restrict__ skW, const float* __restrict__ skb,
                    float* __restrict__ hout, float* __restrict__ partial, int N) {
    __shared__ float sv[256], sq[256];
    size_t total = (size_t)N * 64;
    size_t stride = (size_t)gridDim.x * blockDim.x;
    float s = 0.f, q = 0.f;
    for (size_t idx = (size_t)blockIdx.x * blockDim.x + threadIdx.x; idx < total; idx += stride) {
        int n = (int)(idx >> 6), d = (int)(idx & 63), h2 = d >> 5;
        const float* ps = &dstat[(size_t)n * 6];
        float den = ps[h2], t0 = ps[2 + h2], t1 = ps[4 + h2];
        float agg = t0 * Wl[d] + t1 * Wl[64 + d] + den * bl[d];
        float hv = agg / (den + 1e-16f) + bias1[d]
                 + x[2 * n] * skW[d] + x[2 * n + 1] * skW[64 + d] + skb[d];
        hout[idx] = hv;
        s += hv; q += hv * hv;
    }
    sv[threadIdx.x] = s; sq[threadIdx.x] = q;
    __syncthreads();
    if (threadIdx.x < 64) {
        float a = sv[threadIdx.x] + sv[threadIdx.x + 64] + sv[threadIdx.x + 128] + sv[threadIdx.x + 192];
        float b = sq[threadIdx.x] + sq[threadIdx.x + 64] + sq[threadIdx.x + 128] + sq[threadIdx.x + 192];
        partial[(size_t)blockIdx.x * 128 + threadIdx.x] = a;
        partial[(size_t)blockIdx.x * 128 + 64 + threadIdx.x] = b;
    }
}

// ---- Kred: reduce per-block BN partials ----
__global__ void kred(const float* __restrict__ partial, float* __restrict__ bnstat, int G) {
    __shared__ float sm[256];
    int c = blockIdx.x;
    float s = 0.f;
    for (int i = threadIdx.x; i < G; i += blockDim.x) s += partial[(size_t)i * 128 + c];
    sm[threadIdx.x] = s;
    __syncthreads();
    for (int off = 128; off >= 1; off >>= 1) {
        if (threadIdx.x < off) sm[threadIdx.x] += sm[threadIdx.x + off];
        __syncthreads();
    }
    if (threadIdx.x == 0) bnstat[c] = sm[0];
}

// ---- k3b: mu, rstd ----
__global__ void k3b(const float* __restrict__ bnsum, const float* __restrict__ bnsq,
                    float* __restrict__ mu, float* __restrict__ rstd, int N) {
    int d = threadIdx.x;
    float m = bnsum[d] / (float)N;
    float v = bnsq[d] / (float)N - m * m;
    mu[d] = m;
    rstd[d] = rsqrtf(v + 1e-5f);
}

// ---- k3c: BN + ELU -> xl2, xr2 (wave per node) ----
__global__ void k3c(const float* __restrict__ h, const float* __restrict__ mu,
                    const float* __restrict__ rstd, const float* __restrict__ gamma,
                    const float* __restrict__ beta,
                    const float* __restrict__ Wl, const float* __restrict__ bl,
                    const float* __restrict__ Wr, const float* __restrict__ br,
                    float* __restrict__ xl2, float* __restrict__ xr2, int N) {
    __shared__ float sh[4][64];
    int w = threadIdx.x >> 6, lane = threadIdx.x & 63;
    int n = blockIdx.x * 4 + w;
    bool valid = (n < N);
    if (valid) {
        float hv = h[(size_t)n * 64 + lane];
        hv = (hv - mu[lane]) * rstd[lane] * gamma[lane] + beta[lane];
        sh[w][lane] = elu1(hv);
    }
    __syncthreads();
    if (!valid) return;
    int c = lane & 31;
    const float* W = (lane < 32) ? Wl : Wr;
    const float* b = (lane < 32) ? bl : br;
    float acc = b[c];
    #pragma unroll
    for (int k = 0; k < 64; ++k) acc += sh[w][k] * W[k * 32 + c];
    ((lane < 32) ? xl2 : xr2)[(size_t)n * 32 + c] = acc;
}

// ---- kL2: 32 lanes per node, 4-way edge unroll: 4 independent gather->reduce->exp
//      chains in flight to hide L2 latency. No atomics, no max-sub. ----
__global__ void kL2(const float* __restrict__ xl2, const float* __restrict__ xr2,
                    const int4* __restrict__ edgeS,
                    const int* __restrict__ rowst, const int* __restrict__ cntA,
                    const float* __restrict__ We, const float* __restrict__ att,
                    float* __restrict__ evbuf, float* __restrict__ h2,
                    float* __restrict__ denom2, int N) {
    int g = blockIdx.x * blockDim.x + threadIdx.x;
    int n = g >> 5, c = g & 31;
    if (n >= N) return;
    float wev = We[c], attv = att[c];
    float xrv = xr2[(size_t)n * 32 + c];
    int start = rowst[n], len = cntA[n] + 1;
    float den = 0.f, acc = 0.f;
    int i = 0;
    for (; i + 4 <= len; i += 4) {
        int4 a0 = edgeS[start + i];
        int4 a1 = edgeS[start + i + 1];
        int4 a2 = edgeS[start + i + 2];
        int4 a3 = edgeS[start + i + 3];
        float x0 = xl2[(size_t)a0.x * 32 + c];
        float x1 = xl2[(size_t)a1.x * 32 + c];
        float x2 = xl2[(size_t)a2.x * 32 + c];
        float x3 = xl2[(size_t)a3.x * 32 + c];
        float p0 = lrelu(x0 + xrv + __int_as_float(a0.y) * wev) * attv;
        float p1 = lrelu(x1 + xrv + __int_as_float(a1.y) * wev) * attv;
        float p2 = lrelu(x2 + xrv + __int_as_float(a2.y) * wev) * attv;
        float p3 = lrelu(x3 + xrv + __int_as_float(a3.y) * wev) * attv;
        #pragma unroll
        for (int m = 16; m; m >>= 1) {
            p0 += __shfl_xor(p0, m);
            p1 += __shfl_xor(p1, m);
            p2 += __shfl_xor(p2, m);
            p3 += __shfl_xor(p3, m);
        }
        float e0 = expf(p0), e1 = expf(p1), e2 = expf(p2), e3 = expf(p3);
        den += (e0 + e1) + (e2 + e3);
        acc += e0 * x0 + e1 * x1 + e2 * x2 + e3 * x3;
        if (c == 0) {
            evbuf[a0.z] = e0; evbuf[a1.z] = e1;
            evbuf[a2.z] = e2; evbuf[a3.z] = e3;
        }
    }
    for (; i < len; ++i) {
        int4 e4 = edgeS[start + i];
        float xlv = xl2[(size_t)e4.x * 32 + c];
        float p = lrelu(xlv + xrv + __int_as_float(e4.y) * wev) * attv;
        p = hredsum(p);
        float ev = expf(p);
        den += ev; acc += ev * xlv;
        if (c == 0) evbuf[e4.z] = ev;
    }
    float inv = 1.f / (den + 1e-16f);
    h2[(size_t)n * 32 + c] = acc * inv;
    if (c == 0) denom2[n] = den;
}

// ---- k4c: alpha output (original edge order, coalesced) ----
__global__ void k4c(const float* __restrict__ evbuf, const int* __restrict__ dstA,
                    const float* __restrict__ denom, float* __restrict__ alpha, int E, int Et) {
    int t = blockIdx.x * blockDim.x + threadIdx.x;
    if (t >= Et) return;
    int d = (t < E) ? dstA[t] : (t - E);
    alpha[t] = evbuf[t] / (denom[d] + 1e-16f);
}

// ---- k5: h2 -> +bias2 -> elu -> two streamed MLP heads -> log_softmax ----
__global__ void __launch_bounds__(256, 1)
k5(const float* __restrict__ h2, const float* __restrict__ bias2,
   const float* __restrict__ Wt1, const float* __restrict__ bt1,
   const float* __restrict__ Wt2, const float* __restrict__ bt2,
   const float* __restrict__ Wc1, const float* __restrict__ bc1,
   const float* __restrict__ Wc2, const float* __restrict__ bc2,
   float* __restrict__ out, int N) {
    __shared__ float sWt1[1024], sWc1[1024], sWt2[640], sWc2[320];
    __shared__ float sbt1[32], sbc1[32], sbt2[20], sbc2[10], sb2[32];
    for (int i = threadIdx.x; i < 1024; i += blockDim.x) { sWt1[i] = Wt1[i]; sWc1[i] = Wc1[i]; }
    for (int i = threadIdx.x; i < 640; i += blockDim.x) sWt2[i] = Wt2[i];
    for (int i = threadIdx.x; i < 320; i += blockDim.x) sWc2[i] = Wc2[i];
    if (threadIdx.x < 32) { sbt1[threadIdx.x] = bt1[threadIdx.x]; sbc1[threadIdx.x] = bc1[threadIdx.x]; sb2[threadIdx.x] = bias2[threadIdx.x]; }
    if (threadIdx.x < 20) sbt2[threadIdx.x] = bt2[threadIdx.x];
    if (threadIdx.x < 10) sbc2[threadIdx.x] = bc2[threadIdx.x];
    __syncthreads();
    int n = blockIdx.x * blockDim.x + threadIdx.x;
    if (n >= N) return;
    float h[32];
    #pragma unroll
    for (int k = 0; k < 32; ++k) h[k] = elu1(h2[(size_t)n * 32 + k] + sb2[k]);
    float lt[20], lc[10];
    #pragma unroll
    for (int o = 0; o < 20; ++o) lt[o] = sbt2[o];
    #pragma unroll
    for (int o = 0; o < 10; ++o) lc[o] = sbc2[o];
    #pragma unroll
    for (int j = 0; j < 32; ++j) {
        float at = sbt1[j], ac = sbc1[j];
        #pragma unroll
        for (int k = 0; k < 32; ++k) { at += h[k] * sWt1[k * 32 + j]; ac += h[k] * sWc1[k * 32 + j]; }
        float tj = fmaxf(at, 0.f), cj = fmaxf(ac, 0.f);
        #pragma unroll
        for (int o = 0; o < 20; ++o) lt[o] += tj * sWt2[j * 20 + o];
        #pragma unroll
        for (int o = 0; o < 10; ++o) lc[o] += cj * sWc2[j * 10 + o];
    }
    float mt = -1e30f, mc = -1e30f;
    #pragma unroll
    for (int o = 0; o < 20; ++o) mt = fmaxf(mt, lt[o]);
    #pragma unroll
    for (int o = 0; o < 10; ++o) mc = fmaxf(mc, lc[o]);
    float st = 0.f, sc = 0.f;
    #pragma unroll
    for (int o = 0; o < 20; ++o) st += expf(lt[o] - mt);
    #pragma unroll
    for (int o = 0; o < 10; ++o) sc += expf(lc[o] - mc);
    float lset = mt + logf(st);
    float lsec = mc + logf(sc);
    #pragma unroll
    for (int o = 0; o < 10; ++o) out[(size_t)n * 30 + o] = lc[o] - lsec;
    #pragma unroll
    for (int o = 0; o < 20; ++o) out[(size_t)n * 30 + 10 + o] = lt[o] - lset;
}

extern "C" void kernel_launch(void* const* d_in, const int* in_sizes, int n_in,
                              void* d_out, int out_size, void* d_ws, size_t ws_size,
                              hipStream_t stream) {
    const float* x     = (const float*)d_in[0];
    const int*   ei    = (const int*)d_in[1];
    const float* eattr = (const float*)d_in[2];
    const float* Wl1   = (const float*)d_in[3];
    const float* bl1   = (const float*)d_in[4];
    const float* Wr1   = (const float*)d_in[5];
    const float* br1   = (const float*)d_in[6];
    const float* We1   = (const float*)d_in[7];
    const float* att1  = (const float*)d_in[8];
    const float* bias1 = (const float*)d_in[9];
    const float* skW   = (const float*)d_in[10];
    const float* skb   = (const float*)d_in[11];
    const float* gamma = (const float*)d_in[12];
    const float* beta  = (const float*)d_in[13];
    const float* Wl2   = (const float*)d_in[14];
    const float* bl2   = (const float*)d_in[15];
    const float* Wr2   = (const float*)d_in[16];
    const float* br2   = (const float*)d_in[17];
    const float* We2   = (const float*)d_in[18];
    const float* att2  = (const float*)d_in[19];
    const float* bias2 = (const float*)d_in[20];
    const float* Wc1   = (const float*)d_in[21];
    const float* bc1   = (const float*)d_in[22];
    const float* Wc2   = (const float*)d_in[23];
    const float* bc2   = (const float*)d_in[24];
    const float* Wt1   = (const float*)d_in[25];
    const float* bt1   = (const float*)d_in[26];
    const float* Wt2   = (const float*)d_in[27];
    const float* bt2   = (const float*)d_in[28];

    const int N  = in_sizes[0] / 2;
    const int E  = in_sizes[1] / 2;
    const int Et = E + N;
    const int* srcA = ei;
    const int* dstA = ei + E;
    const int G3 = 1024;
    const int B  = (N + 255) / 256;

    // workspace carve
    char* p = (char*)d_ws;
    unsigned long long* packed = (unsigned long long*)p; p += (size_t)N * 8;
    int*   cursor = (int*)p;   p += (size_t)N * 4;
    int4*  edgeS  = (int4*)p;  p += (size_t)Et * 16;
    float* hbuf   = (float*)p; p += (size_t)N * 64 * 4;   // h rows; reused as h2 (N*32)
    float* xl2    = (float*)p; p += (size_t)N * 32 * 4;
    float* xr2    = (float*)p; p += (size_t)N * 32 * 4;
    float* evbuf  = (float*)p; p += (size_t)Et * 4;
    float* dstat  = (float*)p; p += (size_t)N * 6 * 4;
    int*   cntA   = (int*)p;   p += (size_t)N * 4;
    float* asumA  = (float*)p; p += (size_t)N * 4;
    int*   rowst  = (int*)p;   p += (size_t)N * 4;
    int*   bsum   = (int*)p;   p += 512 * 4;
    float* partial= (float*)p; p += (size_t)G3 * 128 * 4;
    float* bnstat = (float*)p; p += 128 * 4;
    float* mu     = (float*)p; p += 64 * 4;
    float* rstd   = (float*)p; p += 64 * 4;
    float* denom2 = (float*)p; p += (size_t)N * 4;
    float* h2     = hbuf;

    float* outMain  = (float*)d_out;
    float* outAlpha = outMain + (size_t)N * 30;

    // ---- CSR build (atomic-light) ----
    hipMemsetAsync(packed, 0, (size_t)N * 12, stream);    // packed + cursor
    k0p<<<(E + 255) / 256, 256, 0, stream>>>(dstA, eattr, packed, E);
    kscanA<<<B, 256, 0, stream>>>(packed, rowst, bsum, cntA, asumA, N);
    kscanB<<<1, 512, 0, stream>>>(bsum, B);
    kscanC<<<B, 256, 0, stream>>>(rowst, bsum, N);
    kscatter<<<(Et + 255) / 256, 256, 0, stream>>>(srcA, dstA, eattr, asumA, cntA,
                                                   rowst, cursor, edgeS, E, Et);

    // ---- layer 1 (LDS-tiled gather, zero atomics) ----
    kL1<<<(N + 127) / 128, 256, 0, stream>>>(x, edgeS, rowst, cntA,
                                             Wl1, bl1, Wr1, br1, We1, att1,
                                             dstat, N, Et);

    // ---- node reconstruction + skip + BN ----
    k3a<<<G3, 256, 0, stream>>>(x, dstat, Wl1, bl1, bias1, skW, skb, hbuf, partial, N);
    kred<<<128, 256, 0, stream>>>(partial, bnstat, G3);
    k3b<<<1, 64, 0, stream>>>(bnstat, bnstat + 64, mu, rstd, N);
    k3c<<<(N + 3) / 4, 256, 0, stream>>>(hbuf, mu, rstd, gamma, beta,
                                         Wl2, bl2, Wr2, br2, xl2, xr2, N);

    // ---- layer 2 (gather, zero atomics, 4-way unroll) ----
    kL2<<<((size_t)N * 32 + 255) / 256, 256, 0, stream>>>(xl2, xr2, edgeS, rowst, cntA,
                                                          We2, att2, evbuf, h2, denom2, N);
    k4c<<<(Et + 255) / 256, 256, 0, stream>>>(evbuf, dstA, denom2, outAlpha, E, Et);

    // ---- heads ----
    k5<<<(N + 255) / 256, 256, 0, stream>>>(h2, bias2, Wt1, bt1, Wt2, bt2,
                                            Wc1, bc1, Wc2, bc2, outMain, N);
    (void)n_in; (void)out_size; (void)ws_size;
}

// Round 9
// 413.951 us; speedup vs baseline: 9.5691x; 1.0750x over previous
//
#include <hip/hip_runtime.h>
#include <math.h>

#define NEG_SLOPE 0.2f
#define CNT_SHIFT 44
#define EA_SCALE 262144.0f          // 2^18 fixed-point for edge_attr sums
#define EA_INV (1.0f / 262144.0f)
#define L1TILE 3072                 // int4 entries staged in LDS (48 KB)

__device__ __forceinline__ float lrelu(float x) { return x > 0.f ? x : NEG_SLOPE * x; }
__device__ __forceinline__ float elu1(float x) { return x > 0.f ? x : expf(x) - 1.f; }

__device__ __forceinline__ float hredsum(float v) {  // reduce within 32-lane half
    #pragma unroll
    for (int m = 16; m; m >>= 1) v += __shfl_xor(v, m);
    return v;
}

// ---- k0p: one u64 atomic per edge: packed[d] += (1<<44) | fix18(ea) ----
__global__ void k0p(const int* __restrict__ dst, const float* __restrict__ ea,
                    unsigned long long* __restrict__ packed, int E) {
    int t = blockIdx.x * blockDim.x + threadIdx.x;
    if (t >= E) return;
    int d = dst[t];
    unsigned long long inc = (1ULL << CNT_SHIFT)
                           | (unsigned long long)__float2uint_rn(ea[t] * EA_SCALE);
    atomicAdd(&packed[d], inc);
}

// ---- kscanA: per-block inclusive scan of (cnt[i]+1); unpack cnt/asum ----
__global__ void kscanA(const unsigned long long* __restrict__ packed,
                       int* __restrict__ rowstart, int* __restrict__ bsum,
                       int* __restrict__ cntA, float* __restrict__ asumA, int N) {
    __shared__ int sm[256];
    int t = threadIdx.x;
    int i = blockIdx.x * 256 + t;
    int v = 0;
    if (i < N) {
        unsigned long long p = packed[i];
        int c = (int)(p >> CNT_SHIFT);
        cntA[i] = c;
        asumA[i] = (float)(p & ((1ULL << CNT_SHIFT) - 1)) * EA_INV;
        v = c + 1;
    }
    sm[t] = v;
    __syncthreads();
    for (int off = 1; off < 256; off <<= 1) {
        int u = (t >= off) ? sm[t - off] : 0;
        __syncthreads();
        sm[t] += u;
        __syncthreads();
    }
    if (i < N) rowstart[i] = sm[t] - v;
    if (t == 255) bsum[blockIdx.x] = sm[255];
}

__global__ void kscanB(int* __restrict__ bsum, int B) {
    __shared__ int sm[512];
    int t = threadIdx.x;
    int v = (t < B) ? bsum[t] : 0;
    sm[t] = v;
    __syncthreads();
    for (int off = 1; off < 512; off <<= 1) {
        int u = (t >= off) ? sm[t - off] : 0;
        __syncthreads();
        sm[t] += u;
        __syncthreads();
    }
    if (t < B) bsum[t] = sm[t] - v;  // exclusive block offsets
}

__global__ void kscanC(int* __restrict__ rowstart, const int* __restrict__ bsum, int N) {
    int i = blockIdx.x * blockDim.x + threadIdx.x;
    if (i < N) rowstart[i] += bsum[i >> 8];
}

// ---- kscatter: edgeS[pos] = {src, ea_bits, orig, 0}; self-loop slot = cnt[d], no atomic ----
__global__ void kscatter(const int* __restrict__ srcA, const int* __restrict__ dstA,
                         const float* __restrict__ ea, const float* __restrict__ asumA,
                         const int* __restrict__ cntA, const int* __restrict__ rowstart,
                         int* __restrict__ cursor, int4* __restrict__ edgeS, int E, int Et) {
    int t = blockIdx.x * blockDim.x + threadIdx.x;
    if (t >= Et) return;
    if (t < E) {
        int d = dstA[t];
        int c = atomicAdd(&cursor[d], 1);
        int cd = cntA[d];
        int pos = rowstart[d] + min(c, cd - 1);   // clamp keeps replays in-range
        edgeS[pos] = make_int4(srcA[t], __float_as_int(ea[t]), t, 0);
    } else {
        int d = t - E;
        int cd = cntA[d];
        int pos = rowstart[d] + cd;
        float eav = asumA[d] / fmaxf((float)cd, 1.0f);
        edgeS[pos] = make_int4(d, __float_as_int(eav), t, 0);
    }
}

// ---- kL1: LDS-tiled CSR consumption. Block = 128 consecutive nodes x 2 heads. ----
__global__ void __launch_bounds__(256, 2)
kL1(const float* __restrict__ x, const int4* __restrict__ edgeS,
    const int* __restrict__ rowst, const int* __restrict__ cntA,
    const float* __restrict__ Wl, const float* __restrict__ bl,
    const float* __restrict__ Wr, const float* __restrict__ br,
    const float* __restrict__ We, const float* __restrict__ att,
    float* __restrict__ dstat, int N, int Et) {
    __shared__ float sW[7][64];  // wl0, wl1, we, att, wr0, wr1, (bl+br)
    __shared__ int4 sTile[L1TILE];
    if (threadIdx.x < 64) {
        int d = threadIdx.x;
        sW[0][d] = Wl[d];  sW[1][d] = Wl[64 + d];
        sW[2][d] = We[d];  sW[3][d] = att[d];
        sW[4][d] = Wr[d];  sW[5][d] = Wr[64 + d];
        sW[6][d] = bl[d] + br[d];
    }

    int n0 = blockIdx.x * 128;
    int nEnd = min(n0 + 128, N);
    int n = n0 + (threadIdx.x >> 1), h = threadIdx.x & 1;
    bool valid = (n < N);
    int base = h * 32;

    int eStart = rowst[n0];
    int eEnd = (nEnd < N) ? rowst[nEnd] : Et;
    int myStart = 0, myEnd = 0;
    float2 xd = make_float2(0.f, 0.f);
    if (valid) {
        myStart = rowst[n];
        myEnd = myStart + cntA[n] + 1;
        xd = ((const float2*)x)[n];
    }
    __syncthreads();   // sW ready

    float dstp[32];
    #pragma unroll
    for (int c = 0; c < 32; ++c) {
        int dc = base + c;
        dstp[c] = xd.x * sW[4][dc] + xd.y * sW[5][dc] + sW[6][dc];
    }

    float pd = 0.f, pa = 0.f, pb = 0.f;
    for (int tb = eStart; tb < eEnd; tb += L1TILE) {
        int tileLen = min(L1TILE, eEnd - tb);
        __syncthreads();   // previous tile fully consumed
        for (int j = threadIdx.x; j < tileLen; j += 256) sTile[j] = edgeS[tb + j];
        __syncthreads();
        int lo = max(myStart, tb), hi = min(myEnd, tb + tileLen);
        for (int e = lo; e < hi; ++e) {
            int4 e4 = sTile[e - tb];
            float2 xs = ((const float2*)x)[e4.x];
            float eav = __int_as_float(e4.y);
            float l = 0.f;
            #pragma unroll
            for (int c = 0; c < 32; ++c) {
                int dc = base + c;
                float m = dstp[c] + xs.x * sW[0][dc] + xs.y * sW[1][dc] + eav * sW[2][dc];
                l += lrelu(m) * sW[3][dc];
            }
            float ev = expf(l);
            pd += ev; pa += ev * xs.x; pb += ev * xs.y;
        }
    }
    if (valid) {
        dstat[(size_t)n * 6 + h]     = pd;
        dstat[(size_t)n * 6 + 2 + h] = pa;
        dstat[(size_t)n * 6 + 4 + h] = pb;
    }
}

// ---- k3a: reconstruct h = agg/denom + bias1 + skip; BN partials ----
__global__ void k3a(const float* __restrict__ x, const float* __restrict__ dstat,
                    const float* __restrict__ Wl, const float* __restrict__ bl,
                    const float* __restrict__ bias1,
                    const float* __restrict__ skW, const float* __restrict__ skb,
                    float* __restrict__ hout, float* __restrict__ partial, int N) {
    __shared__ float sv[256], sq[256];
    size_t total = (size_t)N * 64;
    size_t stride = (size_t)gridDim.x * blockDim.x;
    float s = 0.f, q = 0.f;
    for (size_t idx = (size_t)blockIdx.x * blockDim.x + threadIdx.x; idx < total; idx += stride) {
        int n = (int)(idx >> 6), d = (int)(idx & 63), h2 = d >> 5;
        const float* ps = &dstat[(size_t)n * 6];
        float den = ps[h2], t0 = ps[2 + h2], t1 = ps[4 + h2];
        float agg = t0 * Wl[d] + t1 * Wl[64 + d] + den * bl[d];
        float hv = agg / (den + 1e-16f) + bias1[d]
                 + x[2 * n] * skW[d] + x[2 * n + 1] * skW[64 + d] + skb[d];
        hout[idx] = hv;
        s += hv; q += hv * hv;
    }
    sv[threadIdx.x] = s; sq[threadIdx.x] = q;
    __syncthreads();
    if (threadIdx.x < 64) {
        float a = sv[threadIdx.x] + sv[threadIdx.x + 64] + sv[threadIdx.x + 128] + sv[threadIdx.x + 192];
        float b = sq[threadIdx.x] + sq[threadIdx.x + 64] + sq[threadIdx.x + 128] + sq[threadIdx.x + 192];
        partial[(size_t)blockIdx.x * 128 + threadIdx.x] = a;
        partial[(size_t)blockIdx.x * 128 + 64 + threadIdx.x] = b;
    }
}

// ---- Kred: reduce per-block BN partials ----
__global__ void kred(const float* __restrict__ partial, float* __restrict__ bnstat, int G) {
    __shared__ float sm[256];
    int c = blockIdx.x;
    float s = 0.f;
    for (int i = threadIdx.x; i < G; i += blockDim.x) s += partial[(size_t)i * 128 + c];
    sm[threadIdx.x] = s;
    __syncthreads();
    for (int off = 128; off >= 1; off >>= 1) {
        if (threadIdx.x < off) sm[threadIdx.x] += sm[threadIdx.x + off];
        __syncthreads();
    }
    if (threadIdx.x == 0) bnstat[c] = sm[0];
}

// ---- k3b: mu, rstd ----
__global__ void k3b(const float* __restrict__ bnsum, const float* __restrict__ bnsq,
                    float* __restrict__ mu, float* __restrict__ rstd, int N) {
    int d = threadIdx.x;
    float m = bnsum[d] / (float)N;
    float v = bnsq[d] / (float)N - m * m;
    mu[d] = m;
    rstd[d] = rsqrtf(v + 1e-5f);
}

// ---- k3c: BN + ELU -> xl2, xr2 (wave per node) ----
__global__ void k3c(const float* __restrict__ h, const float* __restrict__ mu,
                    const float* __restrict__ rstd, const float* __restrict__ gamma,
                    const float* __restrict__ beta,
                    const float* __restrict__ Wl, const float* __restrict__ bl,
                    const float* __restrict__ Wr, const float* __restrict__ br,
                    float* __restrict__ xl2, float* __restrict__ xr2, int N) {
    __shared__ float sh[4][64];
    int w = threadIdx.x >> 6, lane = threadIdx.x & 63;
    int n = blockIdx.x * 4 + w;
    bool valid = (n < N);
    if (valid) {
        float hv = h[(size_t)n * 64 + lane];
        hv = (hv - mu[lane]) * rstd[lane] * gamma[lane] + beta[lane];
        sh[w][lane] = elu1(hv);
    }
    __syncthreads();
    if (!valid) return;
    int c = lane & 31;
    const float* W = (lane < 32) ? Wl : Wr;
    const float* b = (lane < 32) ? bl : br;
    float acc = b[c];
    #pragma unroll
    for (int k = 0; k < 64; ++k) acc += sh[w][k] * W[k * 32 + c];
    ((lane < 32) ? xl2 : xr2)[(size_t)n * 32 + c] = acc;
}

// ---- kL2: 32 lanes per node = 4 edge-slots x 8 channel-lanes (float4/lane).
//      8 edges in flight per node group (2x gated unroll); dot reduce = 3
//      shuffles within 8 lanes; cross-slot reduce once per node. No atomics. ----
__global__ void kL2(const float* __restrict__ xl2, const float* __restrict__ xr2,
                    const int4* __restrict__ edgeS,
                    const int* __restrict__ rowst, const int* __restrict__ cntA,
                    const float* __restrict__ We, const float* __restrict__ att,
                    float* __restrict__ evbuf, float* __restrict__ h2,
                    float* __restrict__ denom2, int N) {
    int g = blockIdx.x * blockDim.x + threadIdx.x;
    int n = g >> 5;
    if (n >= N) return;
    int lane = g & 31;
    int slot = lane >> 3, cl = lane & 7;
    int c4 = cl * 4;
    float4 wev  = *(const float4*)(We + c4);
    float4 attv = *(const float4*)(att + c4);
    float4 xrv  = *(const float4*)(xr2 + (size_t)n * 32 + c4);
    int start = rowst[n], len = cntA[n] + 1;
    float den = 0.f;
    float4 acc = make_float4(0.f, 0.f, 0.f, 0.f);

    for (int base = 0; base < len; base += 8) {
        int iA = base + slot, iB = base + 4 + slot;
        bool aA = iA < len, aB = iB < len;
        int4 eA = edgeS[start + (aA ? iA : 0)];
        int4 eB = edgeS[start + (aB ? iB : 0)];
        float4 xA = *(const float4*)(xl2 + (size_t)eA.x * 32 + c4);
        float4 xB = *(const float4*)(xl2 + (size_t)eB.x * 32 + c4);
        float evA = __int_as_float(eA.y), evB = __int_as_float(eB.y);
        float pA = lrelu(xA.x + xrv.x + evA * wev.x) * attv.x
                 + lrelu(xA.y + xrv.y + evA * wev.y) * attv.y
                 + lrelu(xA.z + xrv.z + evA * wev.z) * attv.z
                 + lrelu(xA.w + xrv.w + evA * wev.w) * attv.w;
        float pB = lrelu(xB.x + xrv.x + evB * wev.x) * attv.x
                 + lrelu(xB.y + xrv.y + evB * wev.y) * attv.y
                 + lrelu(xB.z + xrv.z + evB * wev.z) * attv.z
                 + lrelu(xB.w + xrv.w + evB * wev.w) * attv.w;
        pA += __shfl_xor(pA, 1); pB += __shfl_xor(pB, 1);
        pA += __shfl_xor(pA, 2); pB += __shfl_xor(pB, 2);
        pA += __shfl_xor(pA, 4); pB += __shfl_xor(pB, 4);
        float eevA = aA ? expf(pA) : 0.f;
        float eevB = aB ? expf(pB) : 0.f;
        if (cl == 0) {
            if (aA) evbuf[eA.z] = eevA;
            if (aB) evbuf[eB.z] = eevB;
        }
        den += eevA + eevB;
        acc.x += eevA * xA.x + eevB * xB.x;
        acc.y += eevA * xA.y + eevB * xB.y;
        acc.z += eevA * xA.z + eevB * xB.z;
        acc.w += eevA * xA.w + eevB * xB.w;
    }
    // reduce across the 4 edge-slots (lane bits 3,4)
    #pragma unroll
    for (int m = 8; m <= 16; m <<= 1) {
        den   += __shfl_xor(den, m);
        acc.x += __shfl_xor(acc.x, m);
        acc.y += __shfl_xor(acc.y, m);
        acc.z += __shfl_xor(acc.z, m);
        acc.w += __shfl_xor(acc.w, m);
    }
    float inv = 1.f / (den + 1e-16f);
    if (slot == 0) {
        float4 o = make_float4(acc.x * inv, acc.y * inv, acc.z * inv, acc.w * inv);
        *(float4*)(h2 + (size_t)n * 32 + c4) = o;
    }
    if (lane == 0) denom2[n] = den;
}

// ---- k4c: alpha output (original edge order, coalesced) ----
__global__ void k4c(const float* __restrict__ evbuf, const int* __restrict__ dstA,
                    const float* __restrict__ denom, float* __restrict__ alpha, int E, int Et) {
    int t = blockIdx.x * blockDim.x + threadIdx.x;
    if (t >= Et) return;
    int d = (t < E) ? dstA[t] : (t - E);
    alpha[t] = evbuf[t] / (denom[d] + 1e-16f);
}

// ---- k5: h2 -> +bias2 -> elu -> two streamed MLP heads -> log_softmax ----
__global__ void __launch_bounds__(256, 1)
k5(const float* __restrict__ h2, const float* __restrict__ bias2,
   const float* __restrict__ Wt1, const float* __restrict__ bt1,
   const float* __restrict__ Wt2, const float* __restrict__ bt2,
   const float* __restrict__ Wc1, const float* __restrict__ bc1,
   const float* __restrict__ Wc2, const float* __restrict__ bc2,
   float* __restrict__ out, int N) {
    __shared__ float sWt1[1024], sWc1[1024], sWt2[640], sWc2[320];
    __shared__ float sbt1[32], sbc1[32], sbt2[20], sbc2[10], sb2[32];
    for (int i = threadIdx.x; i < 1024; i += blockDim.x) { sWt1[i] = Wt1[i]; sWc1[i] = Wc1[i]; }
    for (int i = threadIdx.x; i < 640; i += blockDim.x) sWt2[i] = Wt2[i];
    for (int i = threadIdx.x; i < 320; i += blockDim.x) sWc2[i] = Wc2[i];
    if (threadIdx.x < 32) { sbt1[threadIdx.x] = bt1[threadIdx.x]; sbc1[threadIdx.x] = bc1[threadIdx.x]; sb2[threadIdx.x] = bias2[threadIdx.x]; }
    if (threadIdx.x < 20) sbt2[threadIdx.x] = bt2[threadIdx.x];
    if (threadIdx.x < 10) sbc2[threadIdx.x] = bc2[threadIdx.x];
    __syncthreads();
    int n = blockIdx.x * blockDim.x + threadIdx.x;
    if (n >= N) return;
    float h[32];
    #pragma unroll
    for (int k = 0; k < 32; ++k) h[k] = elu1(h2[(size_t)n * 32 + k] + sb2[k]);
    float lt[20], lc[10];
    #pragma unroll
    for (int o = 0; o < 20; ++o) lt[o] = sbt2[o];
    #pragma unroll
    for (int o = 0; o < 10; ++o) lc[o] = sbc2[o];
    #pragma unroll
    for (int j = 0; j < 32; ++j) {
        float at = sbt1[j], ac = sbc1[j];
        #pragma unroll
        for (int k = 0; k < 32; ++k) { at += h[k] * sWt1[k * 32 + j]; ac += h[k] * sWc1[k * 32 + j]; }
        float tj = fmaxf(at, 0.f), cj = fmaxf(ac, 0.f);
        #pragma unroll
        for (int o = 0; o < 20; ++o) lt[o] += tj * sWt2[j * 20 + o];
        #pragma unroll
        for (int o = 0; o < 10; ++o) lc[o] += cj * sWc2[j * 10 + o];
    }
    float mt = -1e30f, mc = -1e30f;
    #pragma unroll
    for (int o = 0; o < 20; ++o) mt = fmaxf(mt, lt[o]);
    #pragma unroll
    for (int o = 0; o < 10; ++o) mc = fmaxf(mc, lc[o]);
    float st = 0.f, sc = 0.f;
    #pragma unroll
    for (int o = 0; o < 20; ++o) st += expf(lt[o] - mt);
    #pragma unroll
    for (int o = 0; o < 10; ++o) sc += expf(lc[o] - mc);
    float lset = mt + logf(st);
    float lsec = mc + logf(sc);
    #pragma unroll
    for (int o = 0; o < 10; ++o) out[(size_t)n * 30 + o] = lc[o] - lsec;
    #pragma unroll
    for (int o = 0; o < 20; ++o) out[(size_t)n * 30 + 10 + o] = lt[o] - lset;
}

extern "C" void kernel_launch(void* const* d_in, const int* in_sizes, int n_in,
                              void* d_out, int out_size, void* d_ws, size_t ws_size,
                              hipStream_t stream) {
    const float* x     = (const float*)d_in[0];
    const int*   ei    = (const int*)d_in[1];
    const float* eattr = (const float*)d_in[2];
    const float* Wl1   = (const float*)d_in[3];
    const float* bl1   = (const float*)d_in[4];
    const float* Wr1   = (const float*)d_in[5];
    const float* br1   = (const float*)d_in[6];
    const float* We1   = (const float*)d_in[7];
    const float* att1  = (const float*)d_in[8];
    const float* bias1 = (const float*)d_in[9];
    const float* skW   = (const float*)d_in[10];
    const float* skb   = (const float*)d_in[11];
    const float* gamma = (const float*)d_in[12];
    const float* beta  = (const float*)d_in[13];
    const float* Wl2   = (const float*)d_in[14];
    const float* bl2   = (const float*)d_in[15];
    const float* Wr2   = (const float*)d_in[16];
    const float* br2   = (const float*)d_in[17];
    const float* We2   = (const float*)d_in[18];
    const float* att2  = (const float*)d_in[19];
    const float* bias2 = (const float*)d_in[20];
    const float* Wc1   = (const float*)d_in[21];
    const float* bc1   = (const float*)d_in[22];
    const float* Wc2   = (const float*)d_in[23];
    const float* bc2   = (const float*)d_in[24];
    const float* Wt1   = (const float*)d_in[25];
    const float* bt1   = (const float*)d_in[26];
    const float* Wt2   = (const float*)d_in[27];
    const float* bt2   = (const float*)d_in[28];

    const int N  = in_sizes[0] / 2;
    const int E  = in_sizes[1] / 2;
    const int Et = E + N;
    const int* srcA = ei;
    const int* dstA = ei + E;
    const int G3 = 1024;
    const int B  = (N + 255) / 256;

    // workspace carve
    char* p = (char*)d_ws;
    unsigned long long* packed = (unsigned long long*)p; p += (size_t)N * 8;
    int*   cursor = (int*)p;   p += (size_t)N * 4;
    int4*  edgeS  = (int4*)p;  p += (size_t)Et * 16;
    float* hbuf   = (float*)p; p += (size_t)N * 64 * 4;   // h rows; reused as h2 (N*32)
    float* xl2    = (float*)p; p += (size_t)N * 32 * 4;
    float* xr2    = (float*)p; p += (size_t)N * 32 * 4;
    float* evbuf  = (float*)p; p += (size_t)Et * 4;
    float* dstat  = (float*)p; p += (size_t)N * 6 * 4;
    int*   cntA   = (int*)p;   p += (size_t)N * 4;
    float* asumA  = (float*)p; p += (size_t)N * 4;
    int*   rowst  = (int*)p;   p += (size_t)N * 4;
    int*   bsum   = (int*)p;   p += 512 * 4;
    float* partial= (float*)p; p += (size_t)G3 * 128 * 4;
    float* bnstat = (float*)p; p += 128 * 4;
    float* mu     = (float*)p; p += 64 * 4;
    float* rstd   = (float*)p; p += 64 * 4;
    float* denom2 = (float*)p; p += (size_t)N * 4;
    float* h2     = hbuf;

    float* outMain  = (float*)d_out;
    float* outAlpha = outMain + (size_t)N * 30;

    // ---- CSR build (atomic-light) ----
    hipMemsetAsync(packed, 0, (size_t)N * 12, stream);    // packed + cursor
    k0p<<<(E + 255) / 256, 256, 0, stream>>>(dstA, eattr, packed, E);
    kscanA<<<B, 256, 0, stream>>>(packed, rowst, bsum, cntA, asumA, N);
    kscanB<<<1, 512, 0, stream>>>(bsum, B);
    kscanC<<<B, 256, 0, stream>>>(rowst, bsum, N);
    kscatter<<<(Et + 255) / 256, 256, 0, stream>>>(srcA, dstA, eattr, asumA, cntA,
                                                   rowst, cursor, edgeS, E, Et);

    // ---- layer 1 (LDS-tiled gather, zero atomics) ----
    kL1<<<(N + 127) / 128, 256, 0, stream>>>(x, edgeS, rowst, cntA,
                                             Wl1, bl1, Wr1, br1, We1, att1,
                                             dstat, N, Et);

    // ---- node reconstruction + skip + BN ----
    k3a<<<G3, 256, 0, stream>>>(x, dstat, Wl1, bl1, bias1, skW, skb, hbuf, partial, N);
    kred<<<128, 256, 0, stream>>>(partial, bnstat, G3);
    k3b<<<1, 64, 0, stream>>>(bnstat, bnstat + 64, mu, rstd, N);
    k3c<<<(N + 3) / 4, 256, 0, stream>>>(hbuf, mu, rstd, gamma, beta,
                                         Wl2, bl2, Wr2, br2, xl2, xr2, N);

    // ---- layer 2 (gather, zero atomics, 4-slot x float4 layout) ----
    kL2<<<((size_t)N * 32 + 255) / 256, 256, 0, stream>>>(xl2, xr2, edgeS, rowst, cntA,
                                                          We2, att2, evbuf, h2, denom2, N);
    k4c<<<(Et + 255) / 256, 256, 0, stream>>>(evbuf, dstA, denom2, outAlpha, E, Et);

    // ---- heads ----
    k5<<<(N + 255) / 256, 256, 0, stream>>>(h2, bias2, Wt1, bt1, Wt2, bt2,
                                            Wc1, bc1, Wc2, bc2, outMain, N);
    (void)n_in; (void)out_size; (void)ws_size;
}